// Round 15
// baseline (2367.912 us; speedup 1.0000x reference)
//
#include <hip/hip_runtime.h>

#define N_PTS 8192
#define B_SZ 4
#define S_PTS 1024
#define K_SMP 32

// ======================= FPS =======================
// One workgroup/batch, 256 threads, 32 points/thread in NAMED REGISTERS
// (macro-generated scalars; r14 profile showed VGPR=84 < 128 needed => the
// array version lived in scratch, ~2500 cyc/iter of L1/L2 traffic).
// Single barrier per iteration: the shfl butterfly carries (v,i,x,y,z) so
// every thread ends each iteration holding far AND its coords in registers
// (no global centroid load, no second barrier, no serial t==0 scan).
// Bit-exact vs r14: same distance chain, same strict-> / lowest-index
// tie-break, same ascending j / ascending wave reduce order.
#define FPS_ALL(M) M(0) M(1) M(2) M(3) M(4) M(5) M(6) M(7) \
                   M(8) M(9) M(10) M(11) M(12) M(13) M(14) M(15) \
                   M(16) M(17) M(18) M(19) M(20) M(21) M(22) M(23) \
                   M(24) M(25) M(26) M(27) M(28) M(29) M(30) M(31)

#define FPS_DECL(J) \
    float px##J = xs[t + J*256], py##J = ys[t + J*256], pz##J = zs[t + J*256], dmin##J = 1e10f;

#define FPS_STEP(J) { \
    float dx = __fsub_rn(px##J, cx); \
    float dy = __fsub_rn(py##J, cy); \
    float dz = __fsub_rn(pz##J, cz); \
    float d  = __fadd_rn(__fadd_rn(__fmul_rn(dx, dx), __fmul_rn(dy, dy)), __fmul_rn(dz, dz)); \
    float dm = fminf(dmin##J, d); \
    dmin##J = dm; \
    if (dm > bestv) { bestv = dm; besti = t + J*256; bx = px##J; by = py##J; bz = pz##J; } \
}

__global__ __launch_bounds__(256, 1) void fps_kernel(
    const float* __restrict__ xyz, int* __restrict__ fps_idx,
    float* __restrict__ out_newxyz)
{
    __shared__ float wv[2][4][4];   // [parity][wave][{v,x,y,z}]
    __shared__ int   wi[2][4];

    const int b = blockIdx.x;
    const int t = threadIdx.x;
    const int wave = t >> 6;
    const int lane = t & 63;
    const float* xs = xyz + (size_t)b * 3 * N_PTS;
    const float* ys = xs + N_PTS;
    const float* zs = ys + N_PTS;

    FPS_ALL(FPS_DECL)

    int far = 0;
    float cx = xs[0], cy = ys[0], cz = zs[0];

    for (int s = 0; s < S_PTS; ++s) {
        if (t == 0) {
            fps_idx[b * S_PTS + s] = far;
            out_newxyz[((size_t)b * 3 + 0) * S_PTS + s] = cx;
            out_newxyz[((size_t)b * 3 + 1) * S_PTS + s] = cy;
            out_newxyz[((size_t)b * 3 + 2) * S_PTS + s] = cz;
        }
        float bestv = -1.0f; int besti = 0;
        float bx = 0.f, by = 0.f, bz = 0.f;
        FPS_ALL(FPS_STEP)

        // 64-lane butterfly argmax carrying coords; tie -> lowest index
#pragma unroll
        for (int off = 32; off >= 1; off >>= 1) {
            float ov = __shfl_xor(bestv, off, 64);
            int   oi = __shfl_xor(besti, off, 64);
            float ox = __shfl_xor(bx, off, 64);
            float oy = __shfl_xor(by, off, 64);
            float oz = __shfl_xor(bz, off, 64);
            if (ov > bestv || (ov == bestv && oi < besti)) {
                bestv = ov; besti = oi; bx = ox; by = oy; bz = oz;
            }
        }
        const int par = s & 1;
        if (lane == 0) {
            wv[par][wave][0] = bestv; wv[par][wave][1] = bx;
            wv[par][wave][2] = by;    wv[par][wave][3] = bz;
            wi[par][wave] = besti;
        }
        __syncthreads();
        // all threads reduce the 4 wave winners in ascending wave order
        float bv = wv[par][0][0]; int bi = wi[par][0];
        float fx = wv[par][0][1], fy = wv[par][0][2], fz = wv[par][0][3];
#pragma unroll
        for (int w = 1; w < 4; ++w) {
            float v2 = wv[par][w][0]; int i2 = wi[par][w];
            if (v2 > bv || (v2 == bv && i2 < bi)) {
                bv = v2; bi = i2;
                fx = wv[par][w][1]; fy = wv[par][w][2]; fz = wv[par][w][3];
            }
        }
        far = bi; cx = fx; cy = fy; cz = fz;
    }
}

// ======================= points transpose (B,D,N) -> (B,N,D) =======================
__global__ __launch_bounds__(256) void transpose_pts_kernel(
    const float* __restrict__ pts, float* __restrict__ ptsT)
{
    __shared__ float T[64][65];
    const int b  = blockIdx.y;
    const int n0 = blockIdx.x * 64;
    const int t  = threadIdx.x;
    const int c  = t & 63;
    const int r0 = (t >> 6) * 16;
#pragma unroll
    for (int rr = 0; rr < 16; ++rr) {
        int d = r0 + rr;
        T[d][c] = pts[((size_t)b * 64 + d) * N_PTS + n0 + c];
    }
    __syncthreads();
#pragma unroll
    for (int rr = 0; rr < 16; ++rr) {
        int n = r0 + rr;
        ptsT[((size_t)b * N_PTS + n0 + n) * 64 + c] = T[c][n];
    }
}

// ======================= ball query ======================= [verified pass r14]
// Association (c): sqr = rn( rn(-2*dot + ps) + cs ), ascNoFMA dot.
__global__ __launch_bounds__(256) void ballq_kernel(
    const float* __restrict__ xyz, const int* __restrict__ fps_idx,
    int* __restrict__ gi)
{
    const int gw   = (blockIdx.x * 256 + threadIdx.x) >> 6;
    const int lane = threadIdx.x & 63;
    const int b = gw >> 10;
    const float* xs = xyz + (size_t)b * 3 * N_PTS;
    const float* ys = xs + N_PTS;
    const float* zs = ys + N_PTS;

    const int fi = fps_idx[gw];
    const float cx = xs[fi], cy = ys[fi], cz = zs[fi];
    const float cs = __fadd_rn(__fadd_rn(__fmul_rn(cx, cx), __fmul_rn(cy, cy)), __fmul_rn(cz, cz));

    int cnt = 0, myidx = 0, firstIdx = 0;
    for (int base = 0; base < N_PTS && cnt < K_SMP; base += 64) {
        int p = base + lane;
        float xx = xs[p], yy = ys[p], zz = zs[p];
        float dot = __fadd_rn(__fadd_rn(__fmul_rn(cx, xx), __fmul_rn(cy, yy)), __fmul_rn(cz, zz));
        float ps  = __fadd_rn(__fadd_rn(__fmul_rn(xx, xx), __fmul_rn(yy, yy)), __fmul_rn(zz, zz));
        float sqr = __fadd_rn(__fadd_rn(__fmul_rn(-2.0f, dot), ps), cs);   // (c)
        bool valid = !(sqr > 0.01f);
        unsigned long long mask = __ballot(valid);
        while (mask && cnt < K_SMP) {
            int bpos = __ffsll((long long)mask) - 1;
            mask &= mask - 1;
            if (cnt == lane) myidx = base + bpos;
            if (cnt == 0)    firstIdx = base + bpos;
            cnt++;
        }
    }
    if (lane < K_SMP) {
        if (lane >= cnt) myidx = firstIdx;
        gi[(size_t)gw * K_SMP + lane] = myidx;
    }
}

// ======================= K1: layer-0 stats only (no y store) =======================
__global__ __launch_bounds__(256) void conv0_stats_kernel(
    const float* __restrict__ xyz, const float* __restrict__ ptsT,
    const int* __restrict__ fps_idx, const int* __restrict__ gi,
    const float* __restrict__ W0, const float* __restrict__ bias0,
    float* __restrict__ stats0)
{
    __shared__ float A[128 * 68];
    __shared__ float Wt[68 * 64];
    __shared__ float cent[4][3];
    __shared__ float bsh[64];
    __shared__ float sred[128];

    const int t = threadIdx.x;
    const size_t pos0 = (size_t)blockIdx.x * 128;
    const int b  = (int)(pos0 >> 15);
    const int s0 = (int)((pos0 >> 5) & (S_PTS - 1));
    const float* xs = xyz + (size_t)b * 3 * N_PTS;
    const float* ys = xs + N_PTS;
    const float* zs = ys + N_PTS;

    if (t < 4) {
        int fi = fps_idx[b * S_PTS + s0 + t];
        cent[t][0] = xs[fi]; cent[t][1] = ys[fi]; cent[t][2] = zs[fi];
    }
    if (t >= 128 && t < 192) bsh[t - 128] = bias0[t - 128];
    if (t >= 192) { sred[t - 192] = 0.f; sred[t - 128] = 0.f; }
    for (int i = t; i < 68 * 64; i += 256) {
        int c = i >> 6, o = i & 63;
        float v = 0.f;
        if (c < 64) v = W0[o * 67 + 3 + c];
        else if (c < 67) v = W0[o * 67 + (c - 64)];
        Wt[i] = v;
    }
    for (int i = t; i < 128 * 16; i += 256) {
        int pos = i >> 4, j = i & 15;
        float4 v = *(const float4*)(ptsT + ((size_t)b * N_PTS + gi[pos0 + pos]) * 64 + j * 4);
        *(float4*)(A + pos * 68 + j * 4) = v;
    }
    __syncthreads();
    if (t < 128) {
        int g = gi[pos0 + t]; int ci = t >> 5;
        A[t * 68 + 64] = __fsub_rn(xs[g], cent[ci][0]);
        A[t * 68 + 65] = __fsub_rn(ys[g], cent[ci][1]);
        A[t * 68 + 66] = __fsub_rn(zs[g], cent[ci][2]);
        A[t * 68 + 67] = 0.f;
    }
    __syncthreads();

    const int og = t & 15;
    const int pg = t >> 4;
    float acc[8][4];
#pragma unroll
    for (int r = 0; r < 8; ++r)
#pragma unroll
        for (int c = 0; c < 4; ++c) acc[r][c] = 0.f;

    for (int j = 0; j < 17; ++j) {
        float w[4][4];
#pragma unroll
        for (int cc = 0; cc < 4; ++cc) {
            float4 v = *(const float4*)(Wt + (j * 4 + cc) * 64 + og * 4);
            w[cc][0] = v.x; w[cc][1] = v.y; w[cc][2] = v.z; w[cc][3] = v.w;
        }
#pragma unroll
        for (int r = 0; r < 8; ++r) {
            float4 v = *(const float4*)(A + (pg + r * 16) * 68 + j * 4);
#pragma unroll
            for (int co = 0; co < 4; ++co) {
                float s = acc[r][co];
                s = fmaf(v.x, w[0][co], s);
                s = fmaf(v.y, w[1][co], s);
                s = fmaf(v.z, w[2][co], s);
                s = fmaf(v.w, w[3][co], s);
                acc[r][co] = s;
            }
        }
    }

    float sum[4] = {0,0,0,0}, ssq[4] = {0,0,0,0};
#pragma unroll
    for (int r = 0; r < 8; ++r)
#pragma unroll
        for (int c = 0; c < 4; ++c) {
            float yv = acc[r][c] + bsh[og * 4 + c];
            sum[c] += yv; ssq[c] = fmaf(yv, yv, ssq[c]);
        }
#pragma unroll
    for (int c = 0; c < 4; ++c) {
        atomicAdd(&sred[og * 4 + c], sum[c]);
        atomicAdd(&sred[64 + og * 4 + c], ssq[c]);
    }
    __syncthreads();
    if (t < 128) atomicAdd(&stats0[t], sred[t]);
}

// ======================= K2: recompute mm0 -> BN0 -> mm1, layer-1 stats =======================
__global__ __launch_bounds__(256) void conv1_stats_kernel(
    const float* __restrict__ xyz, const float* __restrict__ ptsT,
    const int* __restrict__ fps_idx, const int* __restrict__ gi,
    const float* __restrict__ W0, const float* __restrict__ bias0,
    const float* __restrict__ W1, const float* __restrict__ bias1,
    const float* __restrict__ scl0, const float* __restrict__ sh0,
    float* __restrict__ stats1)
{
    __shared__ float A[64 * 68];
    __shared__ float W0t[68 * 64];
    __shared__ float W1t[64 * 64];
    __shared__ float cent[2][3];
    __shared__ float b0sh[64], b1sh[64], s0sh[64], h0sh[64];
    __shared__ float sred[128];

    const int t = threadIdx.x;
    const size_t pos0 = (size_t)blockIdx.x * 64;
    const int b  = (int)(pos0 >> 15);
    const int s0 = (int)((pos0 >> 5) & (S_PTS - 1));
    const float* xs = xyz + (size_t)b * 3 * N_PTS;
    const float* ys = xs + N_PTS;
    const float* zs = ys + N_PTS;

    if (t < 2) {
        int fi = fps_idx[b * S_PTS + s0 + t];
        cent[t][0] = xs[fi]; cent[t][1] = ys[fi]; cent[t][2] = zs[fi];
    }
    if (t >= 64 && t < 128) { b0sh[t-64] = bias0[t-64]; b1sh[t-64] = bias1[t-64]; }
    if (t >= 128 && t < 192) { s0sh[t-128] = scl0[t-128]; h0sh[t-128] = sh0[t-128]; }
    if (t >= 192) { sred[t-192] = 0.f; sred[t-128] = 0.f; }
    for (int i = t; i < 68 * 64; i += 256) {
        int c = i >> 6, o = i & 63;
        float v = 0.f;
        if (c < 64) v = W0[o * 67 + 3 + c];
        else if (c < 67) v = W0[o * 67 + (c - 64)];
        W0t[i] = v;
    }
    for (int i = t; i < 64 * 64; i += 256) { int c = i >> 6, o = i & 63; W1t[i] = W1[o * 64 + c]; }
    for (int i = t; i < 64 * 16; i += 256) {
        int pos = i >> 4, j = i & 15;
        float4 v = *(const float4*)(ptsT + ((size_t)b * N_PTS + gi[pos0 + pos]) * 64 + j * 4);
        *(float4*)(A + pos * 68 + j * 4) = v;
    }
    __syncthreads();
    if (t < 64) {
        int g = gi[pos0 + t]; int ci = t >> 5;
        A[t * 68 + 64] = __fsub_rn(xs[g], cent[ci][0]);
        A[t * 68 + 65] = __fsub_rn(ys[g], cent[ci][1]);
        A[t * 68 + 66] = __fsub_rn(zs[g], cent[ci][2]);
        A[t * 68 + 67] = 0.f;
    }
    __syncthreads();

    const int og = t & 15;
    const int pg = t >> 4;
    float acc[4][4];
#pragma unroll
    for (int r = 0; r < 4; ++r)
#pragma unroll
        for (int c = 0; c < 4; ++c) acc[r][c] = 0.f;

    for (int j = 0; j < 17; ++j) {
        float w[4][4];
#pragma unroll
        for (int cc = 0; cc < 4; ++cc) {
            float4 v = *(const float4*)(W0t + (j * 4 + cc) * 64 + og * 4);
            w[cc][0] = v.x; w[cc][1] = v.y; w[cc][2] = v.z; w[cc][3] = v.w;
        }
#pragma unroll
        for (int r = 0; r < 4; ++r) {
            float4 v = *(const float4*)(A + (pg + r * 16) * 68 + j * 4);
#pragma unroll
            for (int co = 0; co < 4; ++co) {
                float s = acc[r][co];
                s = fmaf(v.x, w[0][co], s);
                s = fmaf(v.y, w[1][co], s);
                s = fmaf(v.z, w[2][co], s);
                s = fmaf(v.w, w[3][co], s);
                acc[r][co] = s;
            }
        }
    }
    __syncthreads();
#pragma unroll
    for (int r = 0; r < 4; ++r) {
        float4 z;
        z.x = fmaxf(fmaf(acc[r][0] + b0sh[og*4+0], s0sh[og*4+0], h0sh[og*4+0]), 0.f);
        z.y = fmaxf(fmaf(acc[r][1] + b0sh[og*4+1], s0sh[og*4+1], h0sh[og*4+1]), 0.f);
        z.z = fmaxf(fmaf(acc[r][2] + b0sh[og*4+2], s0sh[og*4+2], h0sh[og*4+2]), 0.f);
        z.w = fmaxf(fmaf(acc[r][3] + b0sh[og*4+3], s0sh[og*4+3], h0sh[og*4+3]), 0.f);
        *(float4*)(A + (pg + r * 16) * 68 + og * 4) = z;
    }
    __syncthreads();
    float acc1[4][4];
#pragma unroll
    for (int r = 0; r < 4; ++r)
#pragma unroll
        for (int c = 0; c < 4; ++c) acc1[r][c] = 0.f;
    for (int j = 0; j < 16; ++j) {
        float w[4][4];
#pragma unroll
        for (int cc = 0; cc < 4; ++cc) {
            float4 v = *(const float4*)(W1t + (j * 4 + cc) * 64 + og * 4);
            w[cc][0] = v.x; w[cc][1] = v.y; w[cc][2] = v.z; w[cc][3] = v.w;
        }
#pragma unroll
        for (int r = 0; r < 4; ++r) {
            float4 v = *(const float4*)(A + (pg + r * 16) * 68 + j * 4);
#pragma unroll
            for (int co = 0; co < 4; ++co) {
                float s = acc1[r][co];
                s = fmaf(v.x, w[0][co], s);
                s = fmaf(v.y, w[1][co], s);
                s = fmaf(v.z, w[2][co], s);
                s = fmaf(v.w, w[3][co], s);
                acc1[r][co] = s;
            }
        }
    }
    float sum[4] = {0,0,0,0}, ssq[4] = {0,0,0,0};
#pragma unroll
    for (int r = 0; r < 4; ++r)
#pragma unroll
        for (int c = 0; c < 4; ++c) {
            float yv = acc1[r][c] + b1sh[og * 4 + c];
            sum[c] += yv; ssq[c] = fmaf(yv, yv, ssq[c]);
        }
#pragma unroll
    for (int c = 0; c < 4; ++c) {
        atomicAdd(&sred[og * 4 + c], sum[c]);
        atomicAdd(&sred[64 + og * 4 + c], ssq[c]);
    }
    __syncthreads();
    if (t < 128) atomicAdd(&stats1[t], sred[t]);
}

// ======================= K3: full chain -> layer-2 stats + K-max =======================
__global__ __launch_bounds__(256) void conv2_final_kernel(
    const float* __restrict__ xyz, const float* __restrict__ ptsT,
    const int* __restrict__ fps_idx, const int* __restrict__ gi,
    const float* __restrict__ W0, const float* __restrict__ bias0,
    const float* __restrict__ W1, const float* __restrict__ bias1,
    const float* __restrict__ W2, const float* __restrict__ bias2,
    const float* __restrict__ scl0, const float* __restrict__ sh0,
    const float* __restrict__ scl1, const float* __restrict__ sh1,
    float* __restrict__ mout, float* __restrict__ stats2)
{
    __shared__ float A[64 * 68];
    __shared__ float Wb[8192];
    __shared__ float cent[2][3];
    __shared__ float b0sh[64], b1sh[64], b2sh[128];
    __shared__ float s0sh[64], h0sh[64], s1sh[64], h1sh[64];
    __shared__ float sred[256];
    __shared__ float maxbuf[2][8][128];

    const int t = threadIdx.x;
    const size_t pos0 = (size_t)blockIdx.x * 64;
    const int b  = (int)(pos0 >> 15);
    const int s0 = (int)((pos0 >> 5) & (S_PTS - 1));
    const float* xs = xyz + (size_t)b * 3 * N_PTS;
    const float* ys = xs + N_PTS;
    const float* zs = ys + N_PTS;

    if (t < 2) {
        int fi = fps_idx[b * S_PTS + s0 + t];
        cent[t][0] = xs[fi]; cent[t][1] = ys[fi]; cent[t][2] = zs[fi];
    }
    if (t < 64) { s0sh[t] = scl0[t]; h0sh[t] = sh0[t]; }
    else if (t < 128) { s1sh[t-64] = scl1[t-64]; h1sh[t-64] = sh1[t-64]; }
    else if (t < 192) { b0sh[t-128] = bias0[t-128]; b1sh[t-128] = bias1[t-128]; }
    else { int q = (t - 192) * 4; sred[q]=0.f; sred[q+1]=0.f; sred[q+2]=0.f; sred[q+3]=0.f; }
    if (t < 128) b2sh[t] = bias2[t];
    for (int i = t; i < 68 * 64; i += 256) {
        int c = i >> 6, o = i & 63;
        float v = 0.f;
        if (c < 64) v = W0[o * 67 + 3 + c];
        else if (c < 67) v = W0[o * 67 + (c - 64)];
        Wb[i] = v;
    }
    for (int i = t; i < 64 * 16; i += 256) {
        int pos = i >> 4, j = i & 15;
        float4 v = *(const float4*)(ptsT + ((size_t)b * N_PTS + gi[pos0 + pos]) * 64 + j * 4);
        *(float4*)(A + pos * 68 + j * 4) = v;
    }
    __syncthreads();
    if (t < 64) {
        int g = gi[pos0 + t]; int ci = t >> 5;
        A[t * 68 + 64] = __fsub_rn(xs[g], cent[ci][0]);
        A[t * 68 + 65] = __fsub_rn(ys[g], cent[ci][1]);
        A[t * 68 + 66] = __fsub_rn(zs[g], cent[ci][2]);
        A[t * 68 + 67] = 0.f;
    }
    __syncthreads();

    const int og = t & 15;
    const int pg = t >> 4;
    float acc[4][4];
#pragma unroll
    for (int r = 0; r < 4; ++r)
#pragma unroll
        for (int c = 0; c < 4; ++c) acc[r][c] = 0.f;
    for (int j = 0; j < 17; ++j) {
        float w[4][4];
#pragma unroll
        for (int cc = 0; cc < 4; ++cc) {
            float4 v = *(const float4*)(Wb + (j * 4 + cc) * 64 + og * 4);
            w[cc][0] = v.x; w[cc][1] = v.y; w[cc][2] = v.z; w[cc][3] = v.w;
        }
#pragma unroll
        for (int r = 0; r < 4; ++r) {
            float4 v = *(const float4*)(A + (pg + r * 16) * 68 + j * 4);
#pragma unroll
            for (int co = 0; co < 4; ++co) {
                float s = acc[r][co];
                s = fmaf(v.x, w[0][co], s);
                s = fmaf(v.y, w[1][co], s);
                s = fmaf(v.z, w[2][co], s);
                s = fmaf(v.w, w[3][co], s);
                acc[r][co] = s;
            }
        }
    }
    __syncthreads();
#pragma unroll
    for (int r = 0; r < 4; ++r) {
        float4 z;
        z.x = fmaxf(fmaf(acc[r][0] + b0sh[og*4+0], s0sh[og*4+0], h0sh[og*4+0]), 0.f);
        z.y = fmaxf(fmaf(acc[r][1] + b0sh[og*4+1], s0sh[og*4+1], h0sh[og*4+1]), 0.f);
        z.z = fmaxf(fmaf(acc[r][2] + b0sh[og*4+2], s0sh[og*4+2], h0sh[og*4+2]), 0.f);
        z.w = fmaxf(fmaf(acc[r][3] + b0sh[og*4+3], s0sh[og*4+3], h0sh[og*4+3]), 0.f);
        *(float4*)(A + (pg + r * 16) * 68 + og * 4) = z;
    }
    for (int i = t; i < 64 * 64; i += 256) { int c = i >> 6, o = i & 63; Wb[i] = W1[o * 64 + c]; }
    __syncthreads();
    float acc1[4][4];
#pragma unroll
    for (int r = 0; r < 4; ++r)
#pragma unroll
        for (int c = 0; c < 4; ++c) acc1[r][c] = 0.f;
    for (int j = 0; j < 16; ++j) {
        float w[4][4];
#pragma unroll
        for (int cc = 0; cc < 4; ++cc) {
            float4 v = *(const float4*)(Wb + (j * 4 + cc) * 64 + og * 4);
            w[cc][0] = v.x; w[cc][1] = v.y; w[cc][2] = v.z; w[cc][3] = v.w;
        }
#pragma unroll
        for (int r = 0; r < 4; ++r) {
            float4 v = *(const float4*)(A + (pg + r * 16) * 68 + j * 4);
#pragma unroll
            for (int co = 0; co < 4; ++co) {
                float s = acc1[r][co];
                s = fmaf(v.x, w[0][co], s);
                s = fmaf(v.y, w[1][co], s);
                s = fmaf(v.z, w[2][co], s);
                s = fmaf(v.w, w[3][co], s);
                acc1[r][co] = s;
            }
        }
    }
    __syncthreads();
#pragma unroll
    for (int r = 0; r < 4; ++r) {
        float4 z;
        z.x = fmaxf(fmaf(acc1[r][0] + b1sh[og*4+0], s1sh[og*4+0], h1sh[og*4+0]), 0.f);
        z.y = fmaxf(fmaf(acc1[r][1] + b1sh[og*4+1], s1sh[og*4+1], h1sh[og*4+1]), 0.f);
        z.z = fmaxf(fmaf(acc1[r][2] + b1sh[og*4+2], s1sh[og*4+2], h1sh[og*4+2]), 0.f);
        z.w = fmaxf(fmaf(acc1[r][3] + b1sh[og*4+3], s1sh[og*4+3], h1sh[og*4+3]), 0.f);
        *(float4*)(A + (pg + r * 16) * 68 + og * 4) = z;
    }
    for (int i = t; i < 64 * 128; i += 256) { int c = i >> 7, o = i & 127; Wb[i] = W2[o * 64 + c]; }
    __syncthreads();
    const int og2 = t & 31;
    const int pg2 = t >> 5;
    float acc2[8][4];
#pragma unroll
    for (int r = 0; r < 8; ++r)
#pragma unroll
        for (int c = 0; c < 4; ++c) acc2[r][c] = 0.f;
    for (int j = 0; j < 16; ++j) {
        float w[4][4];
#pragma unroll
        for (int cc = 0; cc < 4; ++cc) {
            float4 v = *(const float4*)(Wb + (j * 4 + cc) * 128 + og2 * 4);
            w[cc][0] = v.x; w[cc][1] = v.y; w[cc][2] = v.z; w[cc][3] = v.w;
        }
#pragma unroll
        for (int r = 0; r < 8; ++r) {
            float4 v = *(const float4*)(A + (pg2 + r * 8) * 68 + j * 4);
#pragma unroll
            for (int co = 0; co < 4; ++co) {
                float s = acc2[r][co];
                s = fmaf(v.x, w[0][co], s);
                s = fmaf(v.y, w[1][co], s);
                s = fmaf(v.z, w[2][co], s);
                s = fmaf(v.w, w[3][co], s);
                acc2[r][co] = s;
            }
        }
    }
    float sum[4] = {0,0,0,0}, ssq[4] = {0,0,0,0};
    float mx0[4], mx1[4];
#pragma unroll
    for (int c = 0; c < 4; ++c) { mx0[c] = -3.402823466e38f; mx1[c] = -3.402823466e38f; }
#pragma unroll
    for (int r = 0; r < 8; ++r)
#pragma unroll
        for (int c = 0; c < 4; ++c) {
            float yv = acc2[r][c] + b2sh[og2 * 4 + c];
            sum[c] += yv; ssq[c] = fmaf(yv, yv, ssq[c]);
            if (r < 4) mx0[c] = fmaxf(mx0[c], yv);
            else       mx1[c] = fmaxf(mx1[c], yv);
        }
#pragma unroll
    for (int c = 0; c < 4; ++c) {
        atomicAdd(&sred[og2 * 4 + c], sum[c]);
        atomicAdd(&sred[128 + og2 * 4 + c], ssq[c]);
        maxbuf[0][pg2][og2 * 4 + c] = mx0[c];
        maxbuf[1][pg2][og2 * 4 + c] = mx1[c];
    }
    __syncthreads();
    {
        int cent2 = t >> 7, o = t & 127;
        float v = maxbuf[cent2][0][o];
#pragma unroll
        for (int q = 1; q < 8; ++q) v = fmaxf(v, maxbuf[cent2][q][o]);
        mout[(size_t)(blockIdx.x * 2 + cent2) * 128 + o] = v;
        atomicAdd(&stats2[t], sred[t]);
    }
}

// ======================= BN finalize =======================
__global__ void finalize_kernel(const float* __restrict__ stats, const float* __restrict__ g,
                                const float* __restrict__ beta, float* __restrict__ scl,
                                float* __restrict__ sh, int C)
{
    int c = threadIdx.x;
    if (c >= C) return;
    const float inv = 1.0f / 131072.0f;
    float mean = stats[c] * inv;
    float var  = stats[C + c] * inv - mean * mean;
    var = fmaxf(var, 0.f);
    float s = g[c] / sqrtf(var + 1e-5f);
    scl[c] = s;
    sh[c] = beta[c] - mean * s;
}

// ======================= writeout =======================
__global__ __launch_bounds__(256) void writeout_kernel(
    const float* __restrict__ m, const float* __restrict__ scl,
    const float* __restrict__ sh, float* __restrict__ out)
{
    int idx = blockIdx.x * 256 + threadIdx.x;
    int s = idx & 1023;
    int o = (idx >> 10) & 127;
    int b = idx >> 17;
    float v = m[(size_t)((b << 10) + s) * 128 + o];
    v = fmaxf(fmaf(v, scl[o], sh[o]), 0.f);
    out[idx] = v;
}

// ======================= launch =======================
extern "C" void kernel_launch(void* const* d_in, const int* in_sizes, int n_in,
                              void* d_out, int out_size, void* d_ws, size_t ws_size,
                              hipStream_t stream)
{
    const float* xyz = (const float*)d_in[0];
    const float* pts = (const float*)d_in[1];
    const float* W0  = (const float*)d_in[2];
    const float* b0  = (const float*)d_in[3];
    const float* g0  = (const float*)d_in[4];
    const float* be0 = (const float*)d_in[5];
    const float* W1  = (const float*)d_in[6];
    const float* b1  = (const float*)d_in[7];
    const float* g1  = (const float*)d_in[8];
    const float* be1 = (const float*)d_in[9];
    const float* W2  = (const float*)d_in[10];
    const float* b2  = (const float*)d_in[11];
    const float* g2  = (const float*)d_in[12];
    const float* be2 = (const float*)d_in[13];
    float* out = (float*)d_out;

    char* ws = (char*)d_ws;
    int*   fps_idx = (int*)(ws + 0);              // 16 KB
    int*   gi      = (int*)(ws + 16384);          // 512 KB -> ends 540672
    float* stats   = (float*)(ws + 540672);       // 512 f
    float* ss      = (float*)(ws + 542720);       // 512 f
    float* m       = (float*)(ws + 544768);       // 2 MB
    float* ptsT    = (float*)(ws + 2641920);      // 8 MB -> ends ~10.5 MB
    float *scl0 = ss, *sh0 = ss + 64, *scl1 = ss + 128, *sh1 = ss + 192,
          *scl2 = ss + 256, *sh2 = ss + 384;

    hipMemsetAsync(stats, 0, 2048, stream);

    hipLaunchKernelGGL(fps_kernel, dim3(4), dim3(256), 0, stream, xyz, fps_idx, out);
    hipLaunchKernelGGL(transpose_pts_kernel, dim3(128, 4), dim3(256), 0, stream, pts, ptsT);
    hipLaunchKernelGGL(ballq_kernel, dim3(1024), dim3(256), 0, stream, xyz, fps_idx, gi);
    hipLaunchKernelGGL(conv0_stats_kernel, dim3(1024), dim3(256), 0, stream,
                       xyz, ptsT, fps_idx, gi, W0, b0, stats);
    hipLaunchKernelGGL(finalize_kernel, dim3(1), dim3(64), 0, stream, stats, g0, be0, scl0, sh0, 64);
    hipLaunchKernelGGL(conv1_stats_kernel, dim3(2048), dim3(256), 0, stream,
                       xyz, ptsT, fps_idx, gi, W0, b0, W1, b1, scl0, sh0, stats + 128);
    hipLaunchKernelGGL(finalize_kernel, dim3(1), dim3(64), 0, stream, stats + 128, g1, be1, scl1, sh1, 64);
    hipLaunchKernelGGL(conv2_final_kernel, dim3(2048), dim3(256), 0, stream,
                       xyz, ptsT, fps_idx, gi, W0, b0, W1, b1, W2, b2,
                       scl0, sh0, scl1, sh1, m, stats + 256);
    hipLaunchKernelGGL(finalize_kernel, dim3(1), dim3(128), 0, stream, stats + 256, g2, be2, scl2, sh2, 128);
    hipLaunchKernelGGL(writeout_kernel, dim3(2048), dim3(256), 0, stream, m, scl2, sh2, out + 12288);
}

// Round 16
// 2349.692 us; speedup vs baseline: 1.0078x; 1.0078x over previous
//
#include <hip/hip_runtime.h>

#define N_PTS 8192
#define B_SZ 4
#define S_PTS 1024
#define K_SMP 32

// ======================= FPS =======================
// r15 post-mortem: named scalars alone did NOT force registers (VGPR=84
// unchanged) — the compiler REMATERIALIZED the read-only global loads each
// iteration (96 loads/thread/iter, L1-missing, L2 latency-bound).
// Fix: pin each coordinate with an empty asm "+v" constraint after the
// initial load — the value is "modified" by the asm, so reloading from
// xs[] is no longer a legal recovery; it must stay live in a VGPR.
// Bit-exact vs r14/r15: same distance chain, same strict-> / lowest-index
// tie-break, same ascending j / ascending wave reduce order.
#define FPS_ALL(M) M(0) M(1) M(2) M(3) M(4) M(5) M(6) M(7) \
                   M(8) M(9) M(10) M(11) M(12) M(13) M(14) M(15) \
                   M(16) M(17) M(18) M(19) M(20) M(21) M(22) M(23) \
                   M(24) M(25) M(26) M(27) M(28) M(29) M(30) M(31)

#define FPS_DECL(J) \
    float px##J = xs[t + J*256], py##J = ys[t + J*256], pz##J = zs[t + J*256], dmin##J = 1e10f;

#define FPS_PIN(J) \
    asm volatile("" : "+v"(px##J), "+v"(py##J), "+v"(pz##J));

#define FPS_STEP(J) { \
    float dx = __fsub_rn(px##J, cx); \
    float dy = __fsub_rn(py##J, cy); \
    float dz = __fsub_rn(pz##J, cz); \
    float d  = __fadd_rn(__fadd_rn(__fmul_rn(dx, dx), __fmul_rn(dy, dy)), __fmul_rn(dz, dz)); \
    float dm = fminf(dmin##J, d); \
    dmin##J = dm; \
    if (dm > bestv) { bestv = dm; besti = t + J*256; bx = px##J; by = py##J; bz = pz##J; } \
}

__global__ __launch_bounds__(256, 1) void fps_kernel(
    const float* __restrict__ xyz, int* __restrict__ fps_idx,
    float* __restrict__ out_newxyz)
{
    __shared__ float wv[2][4][4];   // [parity][wave][{v,x,y,z}]
    __shared__ int   wi[2][4];

    const int b = blockIdx.x;
    const int t = threadIdx.x;
    const int wave = t >> 6;
    const int lane = t & 63;
    const float* xs = xyz + (size_t)b * 3 * N_PTS;
    const float* ys = xs + N_PTS;
    const float* zs = ys + N_PTS;

    FPS_ALL(FPS_DECL)
    FPS_ALL(FPS_PIN)

    int far = 0;
    float cx = xs[0], cy = ys[0], cz = zs[0];

    for (int s = 0; s < S_PTS; ++s) {
        if (t == 0) {
            fps_idx[b * S_PTS + s] = far;
            out_newxyz[((size_t)b * 3 + 0) * S_PTS + s] = cx;
            out_newxyz[((size_t)b * 3 + 1) * S_PTS + s] = cy;
            out_newxyz[((size_t)b * 3 + 2) * S_PTS + s] = cz;
        }
        float bestv = -1.0f; int besti = 0;
        float bx = 0.f, by = 0.f, bz = 0.f;
        FPS_ALL(FPS_STEP)

        // 64-lane butterfly argmax carrying coords; tie -> lowest index
#pragma unroll
        for (int off = 32; off >= 1; off >>= 1) {
            float ov = __shfl_xor(bestv, off, 64);
            int   oi = __shfl_xor(besti, off, 64);
            float ox = __shfl_xor(bx, off, 64);
            float oy = __shfl_xor(by, off, 64);
            float oz = __shfl_xor(bz, off, 64);
            if (ov > bestv || (ov == bestv && oi < besti)) {
                bestv = ov; besti = oi; bx = ox; by = oy; bz = oz;
            }
        }
        const int par = s & 1;
        if (lane == 0) {
            wv[par][wave][0] = bestv; wv[par][wave][1] = bx;
            wv[par][wave][2] = by;    wv[par][wave][3] = bz;
            wi[par][wave] = besti;
        }
        __syncthreads();
        // all threads reduce the 4 wave winners in ascending wave order
        float bv = wv[par][0][0]; int bi = wi[par][0];
        float fx = wv[par][0][1], fy = wv[par][0][2], fz = wv[par][0][3];
#pragma unroll
        for (int w = 1; w < 4; ++w) {
            float v2 = wv[par][w][0]; int i2 = wi[par][w];
            if (v2 > bv || (v2 == bv && i2 < bi)) {
                bv = v2; bi = i2;
                fx = wv[par][w][1]; fy = wv[par][w][2]; fz = wv[par][w][3];
            }
        }
        far = bi; cx = fx; cy = fy; cz = fz;
    }
}

// ======================= points transpose (B,D,N) -> (B,N,D) =======================
__global__ __launch_bounds__(256) void transpose_pts_kernel(
    const float* __restrict__ pts, float* __restrict__ ptsT)
{
    __shared__ float T[64][65];
    const int b  = blockIdx.y;
    const int n0 = blockIdx.x * 64;
    const int t  = threadIdx.x;
    const int c  = t & 63;
    const int r0 = (t >> 6) * 16;
#pragma unroll
    for (int rr = 0; rr < 16; ++rr) {
        int d = r0 + rr;
        T[d][c] = pts[((size_t)b * 64 + d) * N_PTS + n0 + c];
    }
    __syncthreads();
#pragma unroll
    for (int rr = 0; rr < 16; ++rr) {
        int n = r0 + rr;
        ptsT[((size_t)b * N_PTS + n0 + n) * 64 + c] = T[c][n];
    }
}

// ======================= ball query ======================= [verified pass r14/r15]
// Association (c): sqr = rn( rn(-2*dot + ps) + cs ), ascNoFMA dot.
__global__ __launch_bounds__(256) void ballq_kernel(
    const float* __restrict__ xyz, const int* __restrict__ fps_idx,
    int* __restrict__ gi)
{
    const int gw   = (blockIdx.x * 256 + threadIdx.x) >> 6;
    const int lane = threadIdx.x & 63;
    const int b = gw >> 10;
    const float* xs = xyz + (size_t)b * 3 * N_PTS;
    const float* ys = xs + N_PTS;
    const float* zs = ys + N_PTS;

    const int fi = fps_idx[gw];
    const float cx = xs[fi], cy = ys[fi], cz = zs[fi];
    const float cs = __fadd_rn(__fadd_rn(__fmul_rn(cx, cx), __fmul_rn(cy, cy)), __fmul_rn(cz, cz));

    int cnt = 0, myidx = 0, firstIdx = 0;
    for (int base = 0; base < N_PTS && cnt < K_SMP; base += 64) {
        int p = base + lane;
        float xx = xs[p], yy = ys[p], zz = zs[p];
        float dot = __fadd_rn(__fadd_rn(__fmul_rn(cx, xx), __fmul_rn(cy, yy)), __fmul_rn(cz, zz));
        float ps  = __fadd_rn(__fadd_rn(__fmul_rn(xx, xx), __fmul_rn(yy, yy)), __fmul_rn(zz, zz));
        float sqr = __fadd_rn(__fadd_rn(__fmul_rn(-2.0f, dot), ps), cs);   // (c)
        bool valid = !(sqr > 0.01f);
        unsigned long long mask = __ballot(valid);
        while (mask && cnt < K_SMP) {
            int bpos = __ffsll((long long)mask) - 1;
            mask &= mask - 1;
            if (cnt == lane) myidx = base + bpos;
            if (cnt == 0)    firstIdx = base + bpos;
            cnt++;
        }
    }
    if (lane < K_SMP) {
        if (lane >= cnt) myidx = firstIdx;
        gi[(size_t)gw * K_SMP + lane] = myidx;
    }
}

// ======================= K1: layer-0 stats only (no y store) =======================
__global__ __launch_bounds__(256) void conv0_stats_kernel(
    const float* __restrict__ xyz, const float* __restrict__ ptsT,
    const int* __restrict__ fps_idx, const int* __restrict__ gi,
    const float* __restrict__ W0, const float* __restrict__ bias0,
    float* __restrict__ stats0)
{
    __shared__ float A[128 * 68];
    __shared__ float Wt[68 * 64];
    __shared__ float cent[4][3];
    __shared__ float bsh[64];
    __shared__ float sred[128];

    const int t = threadIdx.x;
    const size_t pos0 = (size_t)blockIdx.x * 128;
    const int b  = (int)(pos0 >> 15);
    const int s0 = (int)((pos0 >> 5) & (S_PTS - 1));
    const float* xs = xyz + (size_t)b * 3 * N_PTS;
    const float* ys = xs + N_PTS;
    const float* zs = ys + N_PTS;

    if (t < 4) {
        int fi = fps_idx[b * S_PTS + s0 + t];
        cent[t][0] = xs[fi]; cent[t][1] = ys[fi]; cent[t][2] = zs[fi];
    }
    if (t >= 128 && t < 192) bsh[t - 128] = bias0[t - 128];
    if (t >= 192) { sred[t - 192] = 0.f; sred[t - 128] = 0.f; }
    for (int i = t; i < 68 * 64; i += 256) {
        int c = i >> 6, o = i & 63;
        float v = 0.f;
        if (c < 64) v = W0[o * 67 + 3 + c];
        else if (c < 67) v = W0[o * 67 + (c - 64)];
        Wt[i] = v;
    }
    for (int i = t; i < 128 * 16; i += 256) {
        int pos = i >> 4, j = i & 15;
        float4 v = *(const float4*)(ptsT + ((size_t)b * N_PTS + gi[pos0 + pos]) * 64 + j * 4);
        *(float4*)(A + pos * 68 + j * 4) = v;
    }
    __syncthreads();
    if (t < 128) {
        int g = gi[pos0 + t]; int ci = t >> 5;
        A[t * 68 + 64] = __fsub_rn(xs[g], cent[ci][0]);
        A[t * 68 + 65] = __fsub_rn(ys[g], cent[ci][1]);
        A[t * 68 + 66] = __fsub_rn(zs[g], cent[ci][2]);
        A[t * 68 + 67] = 0.f;
    }
    __syncthreads();

    const int og = t & 15;
    const int pg = t >> 4;
    float acc[8][4];
#pragma unroll
    for (int r = 0; r < 8; ++r)
#pragma unroll
        for (int c = 0; c < 4; ++c) acc[r][c] = 0.f;

    for (int j = 0; j < 17; ++j) {
        float w[4][4];
#pragma unroll
        for (int cc = 0; cc < 4; ++cc) {
            float4 v = *(const float4*)(Wt + (j * 4 + cc) * 64 + og * 4);
            w[cc][0] = v.x; w[cc][1] = v.y; w[cc][2] = v.z; w[cc][3] = v.w;
        }
#pragma unroll
        for (int r = 0; r < 8; ++r) {
            float4 v = *(const float4*)(A + (pg + r * 16) * 68 + j * 4);
#pragma unroll
            for (int co = 0; co < 4; ++co) {
                float s = acc[r][co];
                s = fmaf(v.x, w[0][co], s);
                s = fmaf(v.y, w[1][co], s);
                s = fmaf(v.z, w[2][co], s);
                s = fmaf(v.w, w[3][co], s);
                acc[r][co] = s;
            }
        }
    }

    float sum[4] = {0,0,0,0}, ssq[4] = {0,0,0,0};
#pragma unroll
    for (int r = 0; r < 8; ++r)
#pragma unroll
        for (int c = 0; c < 4; ++c) {
            float yv = acc[r][c] + bsh[og * 4 + c];
            sum[c] += yv; ssq[c] = fmaf(yv, yv, ssq[c]);
        }
#pragma unroll
    for (int c = 0; c < 4; ++c) {
        atomicAdd(&sred[og * 4 + c], sum[c]);
        atomicAdd(&sred[64 + og * 4 + c], ssq[c]);
    }
    __syncthreads();
    if (t < 128) atomicAdd(&stats0[t], sred[t]);
}

// ======================= K2: recompute mm0 -> BN0 -> mm1, layer-1 stats =======================
__global__ __launch_bounds__(256) void conv1_stats_kernel(
    const float* __restrict__ xyz, const float* __restrict__ ptsT,
    const int* __restrict__ fps_idx, const int* __restrict__ gi,
    const float* __restrict__ W0, const float* __restrict__ bias0,
    const float* __restrict__ W1, const float* __restrict__ bias1,
    const float* __restrict__ scl0, const float* __restrict__ sh0,
    float* __restrict__ stats1)
{
    __shared__ float A[64 * 68];
    __shared__ float W0t[68 * 64];
    __shared__ float W1t[64 * 64];
    __shared__ float cent[2][3];
    __shared__ float b0sh[64], b1sh[64], s0sh[64], h0sh[64];
    __shared__ float sred[128];

    const int t = threadIdx.x;
    const size_t pos0 = (size_t)blockIdx.x * 64;
    const int b  = (int)(pos0 >> 15);
    const int s0 = (int)((pos0 >> 5) & (S_PTS - 1));
    const float* xs = xyz + (size_t)b * 3 * N_PTS;
    const float* ys = xs + N_PTS;
    const float* zs = ys + N_PTS;

    if (t < 2) {
        int fi = fps_idx[b * S_PTS + s0 + t];
        cent[t][0] = xs[fi]; cent[t][1] = ys[fi]; cent[t][2] = zs[fi];
    }
    if (t >= 64 && t < 128) { b0sh[t-64] = bias0[t-64]; b1sh[t-64] = bias1[t-64]; }
    if (t >= 128 && t < 192) { s0sh[t-128] = scl0[t-128]; h0sh[t-128] = sh0[t-128]; }
    if (t >= 192) { sred[t-192] = 0.f; sred[t-128] = 0.f; }
    for (int i = t; i < 68 * 64; i += 256) {
        int c = i >> 6, o = i & 63;
        float v = 0.f;
        if (c < 64) v = W0[o * 67 + 3 + c];
        else if (c < 67) v = W0[o * 67 + (c - 64)];
        W0t[i] = v;
    }
    for (int i = t; i < 64 * 64; i += 256) { int c = i >> 6, o = i & 63; W1t[i] = W1[o * 64 + c]; }
    for (int i = t; i < 64 * 16; i += 256) {
        int pos = i >> 4, j = i & 15;
        float4 v = *(const float4*)(ptsT + ((size_t)b * N_PTS + gi[pos0 + pos]) * 64 + j * 4);
        *(float4*)(A + pos * 68 + j * 4) = v;
    }
    __syncthreads();
    if (t < 64) {
        int g = gi[pos0 + t]; int ci = t >> 5;
        A[t * 68 + 64] = __fsub_rn(xs[g], cent[ci][0]);
        A[t * 68 + 65] = __fsub_rn(ys[g], cent[ci][1]);
        A[t * 68 + 66] = __fsub_rn(zs[g], cent[ci][2]);
        A[t * 68 + 67] = 0.f;
    }
    __syncthreads();

    const int og = t & 15;
    const int pg = t >> 4;
    float acc[4][4];
#pragma unroll
    for (int r = 0; r < 4; ++r)
#pragma unroll
        for (int c = 0; c < 4; ++c) acc[r][c] = 0.f;

    for (int j = 0; j < 17; ++j) {
        float w[4][4];
#pragma unroll
        for (int cc = 0; cc < 4; ++cc) {
            float4 v = *(const float4*)(W0t + (j * 4 + cc) * 64 + og * 4);
            w[cc][0] = v.x; w[cc][1] = v.y; w[cc][2] = v.z; w[cc][3] = v.w;
        }
#pragma unroll
        for (int r = 0; r < 4; ++r) {
            float4 v = *(const float4*)(A + (pg + r * 16) * 68 + j * 4);
#pragma unroll
            for (int co = 0; co < 4; ++co) {
                float s = acc[r][co];
                s = fmaf(v.x, w[0][co], s);
                s = fmaf(v.y, w[1][co], s);
                s = fmaf(v.z, w[2][co], s);
                s = fmaf(v.w, w[3][co], s);
                acc[r][co] = s;
            }
        }
    }
    __syncthreads();
#pragma unroll
    for (int r = 0; r < 4; ++r) {
        float4 z;
        z.x = fmaxf(fmaf(acc[r][0] + b0sh[og*4+0], s0sh[og*4+0], h0sh[og*4+0]), 0.f);
        z.y = fmaxf(fmaf(acc[r][1] + b0sh[og*4+1], s0sh[og*4+1], h0sh[og*4+1]), 0.f);
        z.z = fmaxf(fmaf(acc[r][2] + b0sh[og*4+2], s0sh[og*4+2], h0sh[og*4+2]), 0.f);
        z.w = fmaxf(fmaf(acc[r][3] + b0sh[og*4+3], s0sh[og*4+3], h0sh[og*4+3]), 0.f);
        *(float4*)(A + (pg + r * 16) * 68 + og * 4) = z;
    }
    __syncthreads();
    float acc1[4][4];
#pragma unroll
    for (int r = 0; r < 4; ++r)
#pragma unroll
        for (int c = 0; c < 4; ++c) acc1[r][c] = 0.f;
    for (int j = 0; j < 16; ++j) {
        float w[4][4];
#pragma unroll
        for (int cc = 0; cc < 4; ++cc) {
            float4 v = *(const float4*)(W1t + (j * 4 + cc) * 64 + og * 4);
            w[cc][0] = v.x; w[cc][1] = v.y; w[cc][2] = v.z; w[cc][3] = v.w;
        }
#pragma unroll
        for (int r = 0; r < 4; ++r) {
            float4 v = *(const float4*)(A + (pg + r * 16) * 68 + j * 4);
#pragma unroll
            for (int co = 0; co < 4; ++co) {
                float s = acc1[r][co];
                s = fmaf(v.x, w[0][co], s);
                s = fmaf(v.y, w[1][co], s);
                s = fmaf(v.z, w[2][co], s);
                s = fmaf(v.w, w[3][co], s);
                acc1[r][co] = s;
            }
        }
    }
    float sum[4] = {0,0,0,0}, ssq[4] = {0,0,0,0};
#pragma unroll
    for (int r = 0; r < 4; ++r)
#pragma unroll
        for (int c = 0; c < 4; ++c) {
            float yv = acc1[r][c] + b1sh[og * 4 + c];
            sum[c] += yv; ssq[c] = fmaf(yv, yv, ssq[c]);
        }
#pragma unroll
    for (int c = 0; c < 4; ++c) {
        atomicAdd(&sred[og * 4 + c], sum[c]);
        atomicAdd(&sred[64 + og * 4 + c], ssq[c]);
    }
    __syncthreads();
    if (t < 128) atomicAdd(&stats1[t], sred[t]);
}

// ======================= K3: full chain -> layer-2 stats + K-max =======================
__global__ __launch_bounds__(256) void conv2_final_kernel(
    const float* __restrict__ xyz, const float* __restrict__ ptsT,
    const int* __restrict__ fps_idx, const int* __restrict__ gi,
    const float* __restrict__ W0, const float* __restrict__ bias0,
    const float* __restrict__ W1, const float* __restrict__ bias1,
    const float* __restrict__ W2, const float* __restrict__ bias2,
    const float* __restrict__ scl0, const float* __restrict__ sh0,
    const float* __restrict__ scl1, const float* __restrict__ sh1,
    float* __restrict__ mout, float* __restrict__ stats2)
{
    __shared__ float A[64 * 68];
    __shared__ float Wb[8192];
    __shared__ float cent[2][3];
    __shared__ float b0sh[64], b1sh[64], b2sh[128];
    __shared__ float s0sh[64], h0sh[64], s1sh[64], h1sh[64];
    __shared__ float sred[256];
    __shared__ float maxbuf[2][8][128];

    const int t = threadIdx.x;
    const size_t pos0 = (size_t)blockIdx.x * 64;
    const int b  = (int)(pos0 >> 15);
    const int s0 = (int)((pos0 >> 5) & (S_PTS - 1));
    const float* xs = xyz + (size_t)b * 3 * N_PTS;
    const float* ys = xs + N_PTS;
    const float* zs = ys + N_PTS;

    if (t < 2) {
        int fi = fps_idx[b * S_PTS + s0 + t];
        cent[t][0] = xs[fi]; cent[t][1] = ys[fi]; cent[t][2] = zs[fi];
    }
    if (t < 64) { s0sh[t] = scl0[t]; h0sh[t] = sh0[t]; }
    else if (t < 128) { s1sh[t-64] = scl1[t-64]; h1sh[t-64] = sh1[t-64]; }
    else if (t < 192) { b0sh[t-128] = bias0[t-128]; b1sh[t-128] = bias1[t-128]; }
    else { int q = (t - 192) * 4; sred[q]=0.f; sred[q+1]=0.f; sred[q+2]=0.f; sred[q+3]=0.f; }
    if (t < 128) b2sh[t] = bias2[t];
    for (int i = t; i < 68 * 64; i += 256) {
        int c = i >> 6, o = i & 63;
        float v = 0.f;
        if (c < 64) v = W0[o * 67 + 3 + c];
        else if (c < 67) v = W0[o * 67 + (c - 64)];
        Wb[i] = v;
    }
    for (int i = t; i < 64 * 16; i += 256) {
        int pos = i >> 4, j = i & 15;
        float4 v = *(const float4*)(ptsT + ((size_t)b * N_PTS + gi[pos0 + pos]) * 64 + j * 4);
        *(float4*)(A + pos * 68 + j * 4) = v;
    }
    __syncthreads();
    if (t < 64) {
        int g = gi[pos0 + t]; int ci = t >> 5;
        A[t * 68 + 64] = __fsub_rn(xs[g], cent[ci][0]);
        A[t * 68 + 65] = __fsub_rn(ys[g], cent[ci][1]);
        A[t * 68 + 66] = __fsub_rn(zs[g], cent[ci][2]);
        A[t * 68 + 67] = 0.f;
    }
    __syncthreads();

    const int og = t & 15;
    const int pg = t >> 4;
    float acc[4][4];
#pragma unroll
    for (int r = 0; r < 4; ++r)
#pragma unroll
        for (int c = 0; c < 4; ++c) acc[r][c] = 0.f;
    for (int j = 0; j < 17; ++j) {
        float w[4][4];
#pragma unroll
        for (int cc = 0; cc < 4; ++cc) {
            float4 v = *(const float4*)(Wb + (j * 4 + cc) * 64 + og * 4);
            w[cc][0] = v.x; w[cc][1] = v.y; w[cc][2] = v.z; w[cc][3] = v.w;
        }
#pragma unroll
        for (int r = 0; r < 4; ++r) {
            float4 v = *(const float4*)(A + (pg + r * 16) * 68 + j * 4);
#pragma unroll
            for (int co = 0; co < 4; ++co) {
                float s = acc[r][co];
                s = fmaf(v.x, w[0][co], s);
                s = fmaf(v.y, w[1][co], s);
                s = fmaf(v.z, w[2][co], s);
                s = fmaf(v.w, w[3][co], s);
                acc[r][co] = s;
            }
        }
    }
    __syncthreads();
#pragma unroll
    for (int r = 0; r < 4; ++r) {
        float4 z;
        z.x = fmaxf(fmaf(acc[r][0] + b0sh[og*4+0], s0sh[og*4+0], h0sh[og*4+0]), 0.f);
        z.y = fmaxf(fmaf(acc[r][1] + b0sh[og*4+1], s0sh[og*4+1], h0sh[og*4+1]), 0.f);
        z.z = fmaxf(fmaf(acc[r][2] + b0sh[og*4+2], s0sh[og*4+2], h0sh[og*4+2]), 0.f);
        z.w = fmaxf(fmaf(acc[r][3] + b0sh[og*4+3], s0sh[og*4+3], h0sh[og*4+3]), 0.f);
        *(float4*)(A + (pg + r * 16) * 68 + og * 4) = z;
    }
    for (int i = t; i < 64 * 64; i += 256) { int c = i >> 6, o = i & 63; Wb[i] = W1[o * 64 + c]; }
    __syncthreads();
    float acc1[4][4];
#pragma unroll
    for (int r = 0; r < 4; ++r)
#pragma unroll
        for (int c = 0; c < 4; ++c) acc1[r][c] = 0.f;
    for (int j = 0; j < 16; ++j) {
        float w[4][4];
#pragma unroll
        for (int cc = 0; cc < 4; ++cc) {
            float4 v = *(const float4*)(Wb + (j * 4 + cc) * 64 + og * 4);
            w[cc][0] = v.x; w[cc][1] = v.y; w[cc][2] = v.z; w[cc][3] = v.w;
        }
#pragma unroll
        for (int r = 0; r < 4; ++r) {
            float4 v = *(const float4*)(A + (pg + r * 16) * 68 + j * 4);
#pragma unroll
            for (int co = 0; co < 4; ++co) {
                float s = acc1[r][co];
                s = fmaf(v.x, w[0][co], s);
                s = fmaf(v.y, w[1][co], s);
                s = fmaf(v.z, w[2][co], s);
                s = fmaf(v.w, w[3][co], s);
                acc1[r][co] = s;
            }
        }
    }
    __syncthreads();
#pragma unroll
    for (int r = 0; r < 4; ++r) {
        float4 z;
        z.x = fmaxf(fmaf(acc1[r][0] + b1sh[og*4+0], s1sh[og*4+0], h1sh[og*4+0]), 0.f);
        z.y = fmaxf(fmaf(acc1[r][1] + b1sh[og*4+1], s1sh[og*4+1], h1sh[og*4+1]), 0.f);
        z.z = fmaxf(fmaf(acc1[r][2] + b1sh[og*4+2], s1sh[og*4+2], h1sh[og*4+2]), 0.f);
        z.w = fmaxf(fmaf(acc1[r][3] + b1sh[og*4+3], s1sh[og*4+3], h1sh[og*4+3]), 0.f);
        *(float4*)(A + (pg + r * 16) * 68 + og * 4) = z;
    }
    for (int i = t; i < 64 * 128; i += 256) { int c = i >> 7, o = i & 127; Wb[i] = W2[o * 64 + c]; }
    __syncthreads();
    const int og2 = t & 31;
    const int pg2 = t >> 5;
    float acc2[8][4];
#pragma unroll
    for (int r = 0; r < 8; ++r)
#pragma unroll
        for (int c = 0; c < 4; ++c) acc2[r][c] = 0.f;
    for (int j = 0; j < 16; ++j) {
        float w[4][4];
#pragma unroll
        for (int cc = 0; cc < 4; ++cc) {
            float4 v = *(const float4*)(Wb + (j * 4 + cc) * 128 + og2 * 4);
            w[cc][0] = v.x; w[cc][1] = v.y; w[cc][2] = v.z; w[cc][3] = v.w;
        }
#pragma unroll
        for (int r = 0; r < 8; ++r) {
            float4 v = *(const float4*)(A + (pg2 + r * 8) * 68 + j * 4);
#pragma unroll
            for (int co = 0; co < 4; ++co) {
                float s = acc2[r][co];
                s = fmaf(v.x, w[0][co], s);
                s = fmaf(v.y, w[1][co], s);
                s = fmaf(v.z, w[2][co], s);
                s = fmaf(v.w, w[3][co], s);
                acc2[r][co] = s;
            }
        }
    }
    float sum[4] = {0,0,0,0}, ssq[4] = {0,0,0,0};
    float mx0[4], mx1[4];
#pragma unroll
    for (int c = 0; c < 4; ++c) { mx0[c] = -3.402823466e38f; mx1[c] = -3.402823466e38f; }
#pragma unroll
    for (int r = 0; r < 8; ++r)
#pragma unroll
        for (int c = 0; c < 4; ++c) {
            float yv = acc2[r][c] + b2sh[og2 * 4 + c];
            sum[c] += yv; ssq[c] = fmaf(yv, yv, ssq[c]);
            if (r < 4) mx0[c] = fmaxf(mx0[c], yv);
            else       mx1[c] = fmaxf(mx1[c], yv);
        }
#pragma unroll
    for (int c = 0; c < 4; ++c) {
        atomicAdd(&sred[og2 * 4 + c], sum[c]);
        atomicAdd(&sred[128 + og2 * 4 + c], ssq[c]);
        maxbuf[0][pg2][og2 * 4 + c] = mx0[c];
        maxbuf[1][pg2][og2 * 4 + c] = mx1[c];
    }
    __syncthreads();
    {
        int cent2 = t >> 7, o = t & 127;
        float v = maxbuf[cent2][0][o];
#pragma unroll
        for (int q = 1; q < 8; ++q) v = fmaxf(v, maxbuf[cent2][q][o]);
        mout[(size_t)(blockIdx.x * 2 + cent2) * 128 + o] = v;
        atomicAdd(&stats2[t], sred[t]);
    }
}

// ======================= BN finalize =======================
__global__ void finalize_kernel(const float* __restrict__ stats, const float* __restrict__ g,
                                const float* __restrict__ beta, float* __restrict__ scl,
                                float* __restrict__ sh, int C)
{
    int c = threadIdx.x;
    if (c >= C) return;
    const float inv = 1.0f / 131072.0f;
    float mean = stats[c] * inv;
    float var  = stats[C + c] * inv - mean * mean;
    var = fmaxf(var, 0.f);
    float s = g[c] / sqrtf(var + 1e-5f);
    scl[c] = s;
    sh[c] = beta[c] - mean * s;
}

// ======================= writeout =======================
__global__ __launch_bounds__(256) void writeout_kernel(
    const float* __restrict__ m, const float* __restrict__ scl,
    const float* __restrict__ sh, float* __restrict__ out)
{
    int idx = blockIdx.x * 256 + threadIdx.x;
    int s = idx & 1023;
    int o = (idx >> 10) & 127;
    int b = idx >> 17;
    float v = m[(size_t)((b << 10) + s) * 128 + o];
    v = fmaxf(fmaf(v, scl[o], sh[o]), 0.f);
    out[idx] = v;
}

// ======================= launch =======================
extern "C" void kernel_launch(void* const* d_in, const int* in_sizes, int n_in,
                              void* d_out, int out_size, void* d_ws, size_t ws_size,
                              hipStream_t stream)
{
    const float* xyz = (const float*)d_in[0];
    const float* pts = (const float*)d_in[1];
    const float* W0  = (const float*)d_in[2];
    const float* b0  = (const float*)d_in[3];
    const float* g0  = (const float*)d_in[4];
    const float* be0 = (const float*)d_in[5];
    const float* W1  = (const float*)d_in[6];
    const float* b1  = (const float*)d_in[7];
    const float* g1  = (const float*)d_in[8];
    const float* be1 = (const float*)d_in[9];
    const float* W2  = (const float*)d_in[10];
    const float* b2  = (const float*)d_in[11];
    const float* g2  = (const float*)d_in[12];
    const float* be2 = (const float*)d_in[13];
    float* out = (float*)d_out;

    char* ws = (char*)d_ws;
    int*   fps_idx = (int*)(ws + 0);              // 16 KB
    int*   gi      = (int*)(ws + 16384);          // 512 KB -> ends 540672
    float* stats   = (float*)(ws + 540672);       // 512 f
    float* ss      = (float*)(ws + 542720);       // 512 f
    float* m       = (float*)(ws + 544768);       // 2 MB
    float* ptsT    = (float*)(ws + 2641920);      // 8 MB -> ends ~10.5 MB
    float *scl0 = ss, *sh0 = ss + 64, *scl1 = ss + 128, *sh1 = ss + 192,
          *scl2 = ss + 256, *sh2 = ss + 384;

    hipMemsetAsync(stats, 0, 2048, stream);

    hipLaunchKernelGGL(fps_kernel, dim3(4), dim3(256), 0, stream, xyz, fps_idx, out);
    hipLaunchKernelGGL(transpose_pts_kernel, dim3(128, 4), dim3(256), 0, stream, pts, ptsT);
    hipLaunchKernelGGL(ballq_kernel, dim3(1024), dim3(256), 0, stream, xyz, fps_idx, gi);
    hipLaunchKernelGGL(conv0_stats_kernel, dim3(1024), dim3(256), 0, stream,
                       xyz, ptsT, fps_idx, gi, W0, b0, stats);
    hipLaunchKernelGGL(finalize_kernel, dim3(1), dim3(64), 0, stream, stats, g0, be0, scl0, sh0, 64);
    hipLaunchKernelGGL(conv1_stats_kernel, dim3(2048), dim3(256), 0, stream,
                       xyz, ptsT, fps_idx, gi, W0, b0, W1, b1, scl0, sh0, stats + 128);
    hipLaunchKernelGGL(finalize_kernel, dim3(1), dim3(64), 0, stream, stats + 128, g1, be1, scl1, sh1, 64);
    hipLaunchKernelGGL(conv2_final_kernel, dim3(2048), dim3(256), 0, stream,
                       xyz, ptsT, fps_idx, gi, W0, b0, W1, b1, W2, b2,
                       scl0, sh0, scl1, sh1, m, stats + 256);
    hipLaunchKernelGGL(finalize_kernel, dim3(1), dim3(128), 0, stream, stats + 256, g2, be2, scl2, sh2, 128);
    hipLaunchKernelGGL(writeout_kernel, dim3(2048), dim3(256), 0, stream, m, scl2, sh2, out + 12288);
}

// Round 17
// 2317.282 us; speedup vs baseline: 1.0218x; 1.0140x over previous
//
#include <hip/hip_runtime.h>

#define N_PTS 8192
#define B_SZ 4
#define S_PTS 1024
#define K_SMP 32

// ======================= FPS =======================
// r16 post-mortem: asm "+v" pins prevent remat but not spill — VGPR stayed 84,
// 2015us. Root cause: 32 pts/thread needs ~128 loop-invariant VGPRs, above the
// allocator's comfort. Fix: 512 threads x 16 pts/thread (64 VGPR of state,
// mirrors r14's in-register dmin[32]) + __launch_bounds__(512,2) (256 VGPR cap)
// + 2 waves/SIMD TLP as fallback latency hiding if remat persists.
// Reduce structure = r15/16's proven single-barrier 5-carry butterfly (bit-
// exact: strict >, lowest-index ties, ascending j then ascending wave).
#define FPS_ALL(M) M(0) M(1) M(2) M(3) M(4) M(5) M(6) M(7) \
                   M(8) M(9) M(10) M(11) M(12) M(13) M(14) M(15)

#define FPS_DECL(J) \
    float px##J = xs[t + J*512], py##J = ys[t + J*512], pz##J = zs[t + J*512], dmin##J = 1e10f;

#define FPS_STEP(J) { \
    float dx = __fsub_rn(px##J, cx); \
    float dy = __fsub_rn(py##J, cy); \
    float dz = __fsub_rn(pz##J, cz); \
    float d  = __fadd_rn(__fadd_rn(__fmul_rn(dx, dx), __fmul_rn(dy, dy)), __fmul_rn(dz, dz)); \
    float dm = fminf(dmin##J, d); \
    dmin##J = dm; \
    if (dm > bestv) { bestv = dm; besti = t + J*512; bx = px##J; by = py##J; bz = pz##J; } \
}

__global__ __launch_bounds__(512, 2) void fps_kernel(
    const float* __restrict__ xyz, int* __restrict__ fps_idx,
    float* __restrict__ out_newxyz)
{
    __shared__ float wv[2][8][4];   // [parity][wave][{v,x,y,z}]
    __shared__ int   wi[2][8];

    const int b = blockIdx.x;
    const int t = threadIdx.x;
    const int wave = t >> 6;
    const int lane = t & 63;
    const float* xs = xyz + (size_t)b * 3 * N_PTS;
    const float* ys = xs + N_PTS;
    const float* zs = ys + N_PTS;

    FPS_ALL(FPS_DECL)

    int far = 0;
    float cx = xs[0], cy = ys[0], cz = zs[0];

    for (int s = 0; s < S_PTS; ++s) {
        if (t == 0) {
            fps_idx[b * S_PTS + s] = far;
            out_newxyz[((size_t)b * 3 + 0) * S_PTS + s] = cx;
            out_newxyz[((size_t)b * 3 + 1) * S_PTS + s] = cy;
            out_newxyz[((size_t)b * 3 + 2) * S_PTS + s] = cz;
        }
        float bestv = -1.0f; int besti = 0;
        float bx = 0.f, by = 0.f, bz = 0.f;
        FPS_ALL(FPS_STEP)

        // 64-lane butterfly argmax carrying coords; tie -> lowest index
#pragma unroll
        for (int off = 32; off >= 1; off >>= 1) {
            float ov = __shfl_xor(bestv, off, 64);
            int   oi = __shfl_xor(besti, off, 64);
            float ox = __shfl_xor(bx, off, 64);
            float oy = __shfl_xor(by, off, 64);
            float oz = __shfl_xor(bz, off, 64);
            if (ov > bestv || (ov == bestv && oi < besti)) {
                bestv = ov; besti = oi; bx = ox; by = oy; bz = oz;
            }
        }
        const int par = s & 1;
        if (lane == 0) {
            wv[par][wave][0] = bestv; wv[par][wave][1] = bx;
            wv[par][wave][2] = by;    wv[par][wave][3] = bz;
            wi[par][wave] = besti;
        }
        __syncthreads();
        // all threads reduce the 8 wave winners in ascending wave order
        float bv = wv[par][0][0]; int bi = wi[par][0];
        float fx = wv[par][0][1], fy = wv[par][0][2], fz = wv[par][0][3];
#pragma unroll
        for (int w = 1; w < 8; ++w) {
            float v2 = wv[par][w][0]; int i2 = wi[par][w];
            if (v2 > bv || (v2 == bv && i2 < bi)) {
                bv = v2; bi = i2;
                fx = wv[par][w][1]; fy = wv[par][w][2]; fz = wv[par][w][3];
            }
        }
        far = bi; cx = fx; cy = fy; cz = fz;
    }
}

// ======================= points transpose (B,D,N) -> (B,N,D) =======================
__global__ __launch_bounds__(256) void transpose_pts_kernel(
    const float* __restrict__ pts, float* __restrict__ ptsT)
{
    __shared__ float T[64][65];
    const int b  = blockIdx.y;
    const int n0 = blockIdx.x * 64;
    const int t  = threadIdx.x;
    const int c  = t & 63;
    const int r0 = (t >> 6) * 16;
#pragma unroll
    for (int rr = 0; rr < 16; ++rr) {
        int d = r0 + rr;
        T[d][c] = pts[((size_t)b * 64 + d) * N_PTS + n0 + c];
    }
    __syncthreads();
#pragma unroll
    for (int rr = 0; rr < 16; ++rr) {
        int n = r0 + rr;
        ptsT[((size_t)b * N_PTS + n0 + n) * 64 + c] = T[c][n];
    }
}

// ======================= ball query ======================= [verified pass r14-r16]
// Association (c): sqr = rn( rn(-2*dot + ps) + cs ), ascNoFMA dot.
__global__ __launch_bounds__(256) void ballq_kernel(
    const float* __restrict__ xyz, const int* __restrict__ fps_idx,
    int* __restrict__ gi)
{
    const int gw   = (blockIdx.x * 256 + threadIdx.x) >> 6;
    const int lane = threadIdx.x & 63;
    const int b = gw >> 10;
    const float* xs = xyz + (size_t)b * 3 * N_PTS;
    const float* ys = xs + N_PTS;
    const float* zs = ys + N_PTS;

    const int fi = fps_idx[gw];
    const float cx = xs[fi], cy = ys[fi], cz = zs[fi];
    const float cs = __fadd_rn(__fadd_rn(__fmul_rn(cx, cx), __fmul_rn(cy, cy)), __fmul_rn(cz, cz));

    int cnt = 0, myidx = 0, firstIdx = 0;
    for (int base = 0; base < N_PTS && cnt < K_SMP; base += 64) {
        int p = base + lane;
        float xx = xs[p], yy = ys[p], zz = zs[p];
        float dot = __fadd_rn(__fadd_rn(__fmul_rn(cx, xx), __fmul_rn(cy, yy)), __fmul_rn(cz, zz));
        float ps  = __fadd_rn(__fadd_rn(__fmul_rn(xx, xx), __fmul_rn(yy, yy)), __fmul_rn(zz, zz));
        float sqr = __fadd_rn(__fadd_rn(__fmul_rn(-2.0f, dot), ps), cs);   // (c)
        bool valid = !(sqr > 0.01f);
        unsigned long long mask = __ballot(valid);
        while (mask && cnt < K_SMP) {
            int bpos = __ffsll((long long)mask) - 1;
            mask &= mask - 1;
            if (cnt == lane) myidx = base + bpos;
            if (cnt == 0)    firstIdx = base + bpos;
            cnt++;
        }
    }
    if (lane < K_SMP) {
        if (lane >= cnt) myidx = firstIdx;
        gi[(size_t)gw * K_SMP + lane] = myidx;
    }
}

// ======================= K1: layer-0 stats only (no y store) =======================
__global__ __launch_bounds__(256) void conv0_stats_kernel(
    const float* __restrict__ xyz, const float* __restrict__ ptsT,
    const int* __restrict__ fps_idx, const int* __restrict__ gi,
    const float* __restrict__ W0, const float* __restrict__ bias0,
    float* __restrict__ stats0)
{
    __shared__ float A[128 * 68];
    __shared__ float Wt[68 * 64];
    __shared__ float cent[4][3];
    __shared__ float bsh[64];
    __shared__ float sred[128];

    const int t = threadIdx.x;
    const size_t pos0 = (size_t)blockIdx.x * 128;
    const int b  = (int)(pos0 >> 15);
    const int s0 = (int)((pos0 >> 5) & (S_PTS - 1));
    const float* xs = xyz + (size_t)b * 3 * N_PTS;
    const float* ys = xs + N_PTS;
    const float* zs = ys + N_PTS;

    if (t < 4) {
        int fi = fps_idx[b * S_PTS + s0 + t];
        cent[t][0] = xs[fi]; cent[t][1] = ys[fi]; cent[t][2] = zs[fi];
    }
    if (t >= 128 && t < 192) bsh[t - 128] = bias0[t - 128];
    if (t >= 192) { sred[t - 192] = 0.f; sred[t - 128] = 0.f; }
    for (int i = t; i < 68 * 64; i += 256) {
        int c = i >> 6, o = i & 63;
        float v = 0.f;
        if (c < 64) v = W0[o * 67 + 3 + c];
        else if (c < 67) v = W0[o * 67 + (c - 64)];
        Wt[i] = v;
    }
    for (int i = t; i < 128 * 16; i += 256) {
        int pos = i >> 4, j = i & 15;
        float4 v = *(const float4*)(ptsT + ((size_t)b * N_PTS + gi[pos0 + pos]) * 64 + j * 4);
        *(float4*)(A + pos * 68 + j * 4) = v;
    }
    __syncthreads();
    if (t < 128) {
        int g = gi[pos0 + t]; int ci = t >> 5;
        A[t * 68 + 64] = __fsub_rn(xs[g], cent[ci][0]);
        A[t * 68 + 65] = __fsub_rn(ys[g], cent[ci][1]);
        A[t * 68 + 66] = __fsub_rn(zs[g], cent[ci][2]);
        A[t * 68 + 67] = 0.f;
    }
    __syncthreads();

    const int og = t & 15;
    const int pg = t >> 4;
    float acc[8][4];
#pragma unroll
    for (int r = 0; r < 8; ++r)
#pragma unroll
        for (int c = 0; c < 4; ++c) acc[r][c] = 0.f;

    for (int j = 0; j < 17; ++j) {
        float w[4][4];
#pragma unroll
        for (int cc = 0; cc < 4; ++cc) {
            float4 v = *(const float4*)(Wt + (j * 4 + cc) * 64 + og * 4);
            w[cc][0] = v.x; w[cc][1] = v.y; w[cc][2] = v.z; w[cc][3] = v.w;
        }
#pragma unroll
        for (int r = 0; r < 8; ++r) {
            float4 v = *(const float4*)(A + (pg + r * 16) * 68 + j * 4);
#pragma unroll
            for (int co = 0; co < 4; ++co) {
                float s = acc[r][co];
                s = fmaf(v.x, w[0][co], s);
                s = fmaf(v.y, w[1][co], s);
                s = fmaf(v.z, w[2][co], s);
                s = fmaf(v.w, w[3][co], s);
                acc[r][co] = s;
            }
        }
    }

    float sum[4] = {0,0,0,0}, ssq[4] = {0,0,0,0};
#pragma unroll
    for (int r = 0; r < 8; ++r)
#pragma unroll
        for (int c = 0; c < 4; ++c) {
            float yv = acc[r][c] + bsh[og * 4 + c];
            sum[c] += yv; ssq[c] = fmaf(yv, yv, ssq[c]);
        }
#pragma unroll
    for (int c = 0; c < 4; ++c) {
        atomicAdd(&sred[og * 4 + c], sum[c]);
        atomicAdd(&sred[64 + og * 4 + c], ssq[c]);
    }
    __syncthreads();
    if (t < 128) atomicAdd(&stats0[t], sred[t]);
}

// ======================= K2: recompute mm0 -> BN0 -> mm1, layer-1 stats =======================
__global__ __launch_bounds__(256) void conv1_stats_kernel(
    const float* __restrict__ xyz, const float* __restrict__ ptsT,
    const int* __restrict__ fps_idx, const int* __restrict__ gi,
    const float* __restrict__ W0, const float* __restrict__ bias0,
    const float* __restrict__ W1, const float* __restrict__ bias1,
    const float* __restrict__ scl0, const float* __restrict__ sh0,
    float* __restrict__ stats1)
{
    __shared__ float A[64 * 68];
    __shared__ float W0t[68 * 64];
    __shared__ float W1t[64 * 64];
    __shared__ float cent[2][3];
    __shared__ float b0sh[64], b1sh[64], s0sh[64], h0sh[64];
    __shared__ float sred[128];

    const int t = threadIdx.x;
    const size_t pos0 = (size_t)blockIdx.x * 64;
    const int b  = (int)(pos0 >> 15);
    const int s0 = (int)((pos0 >> 5) & (S_PTS - 1));
    const float* xs = xyz + (size_t)b * 3 * N_PTS;
    const float* ys = xs + N_PTS;
    const float* zs = ys + N_PTS;

    if (t < 2) {
        int fi = fps_idx[b * S_PTS + s0 + t];
        cent[t][0] = xs[fi]; cent[t][1] = ys[fi]; cent[t][2] = zs[fi];
    }
    if (t >= 64 && t < 128) { b0sh[t-64] = bias0[t-64]; b1sh[t-64] = bias1[t-64]; }
    if (t >= 128 && t < 192) { s0sh[t-128] = scl0[t-128]; h0sh[t-128] = sh0[t-128]; }
    if (t >= 192) { sred[t-192] = 0.f; sred[t-128] = 0.f; }
    for (int i = t; i < 68 * 64; i += 256) {
        int c = i >> 6, o = i & 63;
        float v = 0.f;
        if (c < 64) v = W0[o * 67 + 3 + c];
        else if (c < 67) v = W0[o * 67 + (c - 64)];
        W0t[i] = v;
    }
    for (int i = t; i < 64 * 64; i += 256) { int c = i >> 6, o = i & 63; W1t[i] = W1[o * 64 + c]; }
    for (int i = t; i < 64 * 16; i += 256) {
        int pos = i >> 4, j = i & 15;
        float4 v = *(const float4*)(ptsT + ((size_t)b * N_PTS + gi[pos0 + pos]) * 64 + j * 4);
        *(float4*)(A + pos * 68 + j * 4) = v;
    }
    __syncthreads();
    if (t < 64) {
        int g = gi[pos0 + t]; int ci = t >> 5;
        A[t * 68 + 64] = __fsub_rn(xs[g], cent[ci][0]);
        A[t * 68 + 65] = __fsub_rn(ys[g], cent[ci][1]);
        A[t * 68 + 66] = __fsub_rn(zs[g], cent[ci][2]);
        A[t * 68 + 67] = 0.f;
    }
    __syncthreads();

    const int og = t & 15;
    const int pg = t >> 4;
    float acc[4][4];
#pragma unroll
    for (int r = 0; r < 4; ++r)
#pragma unroll
        for (int c = 0; c < 4; ++c) acc[r][c] = 0.f;

    for (int j = 0; j < 17; ++j) {
        float w[4][4];
#pragma unroll
        for (int cc = 0; cc < 4; ++cc) {
            float4 v = *(const float4*)(W0t + (j * 4 + cc) * 64 + og * 4);
            w[cc][0] = v.x; w[cc][1] = v.y; w[cc][2] = v.z; w[cc][3] = v.w;
        }
#pragma unroll
        for (int r = 0; r < 4; ++r) {
            float4 v = *(const float4*)(A + (pg + r * 16) * 68 + j * 4);
#pragma unroll
            for (int co = 0; co < 4; ++co) {
                float s = acc[r][co];
                s = fmaf(v.x, w[0][co], s);
                s = fmaf(v.y, w[1][co], s);
                s = fmaf(v.z, w[2][co], s);
                s = fmaf(v.w, w[3][co], s);
                acc[r][co] = s;
            }
        }
    }
    __syncthreads();
#pragma unroll
    for (int r = 0; r < 4; ++r) {
        float4 z;
        z.x = fmaxf(fmaf(acc[r][0] + b0sh[og*4+0], s0sh[og*4+0], h0sh[og*4+0]), 0.f);
        z.y = fmaxf(fmaf(acc[r][1] + b0sh[og*4+1], s0sh[og*4+1], h0sh[og*4+1]), 0.f);
        z.z = fmaxf(fmaf(acc[r][2] + b0sh[og*4+2], s0sh[og*4+2], h0sh[og*4+2]), 0.f);
        z.w = fmaxf(fmaf(acc[r][3] + b0sh[og*4+3], s0sh[og*4+3], h0sh[og*4+3]), 0.f);
        *(float4*)(A + (pg + r * 16) * 68 + og * 4) = z;
    }
    __syncthreads();
    float acc1[4][4];
#pragma unroll
    for (int r = 0; r < 4; ++r)
#pragma unroll
        for (int c = 0; c < 4; ++c) acc1[r][c] = 0.f;
    for (int j = 0; j < 16; ++j) {
        float w[4][4];
#pragma unroll
        for (int cc = 0; cc < 4; ++cc) {
            float4 v = *(const float4*)(W1t + (j * 4 + cc) * 64 + og * 4);
            w[cc][0] = v.x; w[cc][1] = v.y; w[cc][2] = v.z; w[cc][3] = v.w;
        }
#pragma unroll
        for (int r = 0; r < 4; ++r) {
            float4 v = *(const float4*)(A + (pg + r * 16) * 68 + j * 4);
#pragma unroll
            for (int co = 0; co < 4; ++co) {
                float s = acc1[r][co];
                s = fmaf(v.x, w[0][co], s);
                s = fmaf(v.y, w[1][co], s);
                s = fmaf(v.z, w[2][co], s);
                s = fmaf(v.w, w[3][co], s);
                acc1[r][co] = s;
            }
        }
    }
    float sum[4] = {0,0,0,0}, ssq[4] = {0,0,0,0};
#pragma unroll
    for (int r = 0; r < 4; ++r)
#pragma unroll
        for (int c = 0; c < 4; ++c) {
            float yv = acc1[r][c] + b1sh[og * 4 + c];
            sum[c] += yv; ssq[c] = fmaf(yv, yv, ssq[c]);
        }
#pragma unroll
    for (int c = 0; c < 4; ++c) {
        atomicAdd(&sred[og * 4 + c], sum[c]);
        atomicAdd(&sred[64 + og * 4 + c], ssq[c]);
    }
    __syncthreads();
    if (t < 128) atomicAdd(&stats1[t], sred[t]);
}

// ======================= K3: full chain -> layer-2 stats + K-max =======================
__global__ __launch_bounds__(256) void conv2_final_kernel(
    const float* __restrict__ xyz, const float* __restrict__ ptsT,
    const int* __restrict__ fps_idx, const int* __restrict__ gi,
    const float* __restrict__ W0, const float* __restrict__ bias0,
    const float* __restrict__ W1, const float* __restrict__ bias1,
    const float* __restrict__ W2, const float* __restrict__ bias2,
    const float* __restrict__ scl0, const float* __restrict__ sh0,
    const float* __restrict__ scl1, const float* __restrict__ sh1,
    float* __restrict__ mout, float* __restrict__ stats2)
{
    __shared__ float A[64 * 68];
    __shared__ float Wb[8192];
    __shared__ float cent[2][3];
    __shared__ float b0sh[64], b1sh[64], b2sh[128];
    __shared__ float s0sh[64], h0sh[64], s1sh[64], h1sh[64];
    __shared__ float sred[256];
    __shared__ float maxbuf[2][8][128];

    const int t = threadIdx.x;
    const size_t pos0 = (size_t)blockIdx.x * 64;
    const int b  = (int)(pos0 >> 15);
    const int s0 = (int)((pos0 >> 5) & (S_PTS - 1));
    const float* xs = xyz + (size_t)b * 3 * N_PTS;
    const float* ys = xs + N_PTS;
    const float* zs = ys + N_PTS;

    if (t < 2) {
        int fi = fps_idx[b * S_PTS + s0 + t];
        cent[t][0] = xs[fi]; cent[t][1] = ys[fi]; cent[t][2] = zs[fi];
    }
    if (t < 64) { s0sh[t] = scl0[t]; h0sh[t] = sh0[t]; }
    else if (t < 128) { s1sh[t-64] = scl1[t-64]; h1sh[t-64] = sh1[t-64]; }
    else if (t < 192) { b0sh[t-128] = bias0[t-128]; b1sh[t-128] = bias1[t-128]; }
    else { int q = (t - 192) * 4; sred[q]=0.f; sred[q+1]=0.f; sred[q+2]=0.f; sred[q+3]=0.f; }
    if (t < 128) b2sh[t] = bias2[t];
    for (int i = t; i < 68 * 64; i += 256) {
        int c = i >> 6, o = i & 63;
        float v = 0.f;
        if (c < 64) v = W0[o * 67 + 3 + c];
        else if (c < 67) v = W0[o * 67 + (c - 64)];
        Wb[i] = v;
    }
    for (int i = t; i < 64 * 16; i += 256) {
        int pos = i >> 4, j = i & 15;
        float4 v = *(const float4*)(ptsT + ((size_t)b * N_PTS + gi[pos0 + pos]) * 64 + j * 4);
        *(float4*)(A + pos * 68 + j * 4) = v;
    }
    __syncthreads();
    if (t < 64) {
        int g = gi[pos0 + t]; int ci = t >> 5;
        A[t * 68 + 64] = __fsub_rn(xs[g], cent[ci][0]);
        A[t * 68 + 65] = __fsub_rn(ys[g], cent[ci][1]);
        A[t * 68 + 66] = __fsub_rn(zs[g], cent[ci][2]);
        A[t * 68 + 67] = 0.f;
    }
    __syncthreads();

    const int og = t & 15;
    const int pg = t >> 4;
    float acc[4][4];
#pragma unroll
    for (int r = 0; r < 4; ++r)
#pragma unroll
        for (int c = 0; c < 4; ++c) acc[r][c] = 0.f;
    for (int j = 0; j < 17; ++j) {
        float w[4][4];
#pragma unroll
        for (int cc = 0; cc < 4; ++cc) {
            float4 v = *(const float4*)(Wb + (j * 4 + cc) * 64 + og * 4);
            w[cc][0] = v.x; w[cc][1] = v.y; w[cc][2] = v.z; w[cc][3] = v.w;
        }
#pragma unroll
        for (int r = 0; r < 4; ++r) {
            float4 v = *(const float4*)(A + (pg + r * 16) * 68 + j * 4);
#pragma unroll
            for (int co = 0; co < 4; ++co) {
                float s = acc[r][co];
                s = fmaf(v.x, w[0][co], s);
                s = fmaf(v.y, w[1][co], s);
                s = fmaf(v.z, w[2][co], s);
                s = fmaf(v.w, w[3][co], s);
                acc[r][co] = s;
            }
        }
    }
    __syncthreads();
#pragma unroll
    for (int r = 0; r < 4; ++r) {
        float4 z;
        z.x = fmaxf(fmaf(acc[r][0] + b0sh[og*4+0], s0sh[og*4+0], h0sh[og*4+0]), 0.f);
        z.y = fmaxf(fmaf(acc[r][1] + b0sh[og*4+1], s0sh[og*4+1], h0sh[og*4+1]), 0.f);
        z.z = fmaxf(fmaf(acc[r][2] + b0sh[og*4+2], s0sh[og*4+2], h0sh[og*4+2]), 0.f);
        z.w = fmaxf(fmaf(acc[r][3] + b0sh[og*4+3], s0sh[og*4+3], h0sh[og*4+3]), 0.f);
        *(float4*)(A + (pg + r * 16) * 68 + og * 4) = z;
    }
    for (int i = t; i < 64 * 64; i += 256) { int c = i >> 6, o = i & 63; Wb[i] = W1[o * 64 + c]; }
    __syncthreads();
    float acc1[4][4];
#pragma unroll
    for (int r = 0; r < 4; ++r)
#pragma unroll
        for (int c = 0; c < 4; ++c) acc1[r][c] = 0.f;
    for (int j = 0; j < 16; ++j) {
        float w[4][4];
#pragma unroll
        for (int cc = 0; cc < 4; ++cc) {
            float4 v = *(const float4*)(Wb + (j * 4 + cc) * 64 + og * 4);
            w[cc][0] = v.x; w[cc][1] = v.y; w[cc][2] = v.z; w[cc][3] = v.w;
        }
#pragma unroll
        for (int r = 0; r < 4; ++r) {
            float4 v = *(const float4*)(A + (pg + r * 16) * 68 + j * 4);
#pragma unroll
            for (int co = 0; co < 4; ++co) {
                float s = acc1[r][co];
                s = fmaf(v.x, w[0][co], s);
                s = fmaf(v.y, w[1][co], s);
                s = fmaf(v.z, w[2][co], s);
                s = fmaf(v.w, w[3][co], s);
                acc1[r][co] = s;
            }
        }
    }
    __syncthreads();
#pragma unroll
    for (int r = 0; r < 4; ++r) {
        float4 z;
        z.x = fmaxf(fmaf(acc1[r][0] + b1sh[og*4+0], s1sh[og*4+0], h1sh[og*4+0]), 0.f);
        z.y = fmaxf(fmaf(acc1[r][1] + b1sh[og*4+1], s1sh[og*4+1], h1sh[og*4+1]), 0.f);
        z.z = fmaxf(fmaf(acc1[r][2] + b1sh[og*4+2], s1sh[og*4+2], h1sh[og*4+2]), 0.f);
        z.w = fmaxf(fmaf(acc1[r][3] + b1sh[og*4+3], s1sh[og*4+3], h1sh[og*4+3]), 0.f);
        *(float4*)(A + (pg + r * 16) * 68 + og * 4) = z;
    }
    for (int i = t; i < 64 * 128; i += 256) { int c = i >> 7, o = i & 127; Wb[i] = W2[o * 64 + c]; }
    __syncthreads();
    const int og2 = t & 31;
    const int pg2 = t >> 5;
    float acc2[8][4];
#pragma unroll
    for (int r = 0; r < 8; ++r)
#pragma unroll
        for (int c = 0; c < 4; ++c) acc2[r][c] = 0.f;
    for (int j = 0; j < 16; ++j) {
        float w[4][4];
#pragma unroll
        for (int cc = 0; cc < 4; ++cc) {
            float4 v = *(const float4*)(Wb + (j * 4 + cc) * 128 + og2 * 4);
            w[cc][0] = v.x; w[cc][1] = v.y; w[cc][2] = v.z; w[cc][3] = v.w;
        }
#pragma unroll
        for (int r = 0; r < 8; ++r) {
            float4 v = *(const float4*)(A + (pg2 + r * 8) * 68 + j * 4);
#pragma unroll
            for (int co = 0; co < 4; ++co) {
                float s = acc2[r][co];
                s = fmaf(v.x, w[0][co], s);
                s = fmaf(v.y, w[1][co], s);
                s = fmaf(v.z, w[2][co], s);
                s = fmaf(v.w, w[3][co], s);
                acc2[r][co] = s;
            }
        }
    }
    float sum[4] = {0,0,0,0}, ssq[4] = {0,0,0,0};
    float mx0[4], mx1[4];
#pragma unroll
    for (int c = 0; c < 4; ++c) { mx0[c] = -3.402823466e38f; mx1[c] = -3.402823466e38f; }
#pragma unroll
    for (int r = 0; r < 8; ++r)
#pragma unroll
        for (int c = 0; c < 4; ++c) {
            float yv = acc2[r][c] + b2sh[og2 * 4 + c];
            sum[c] += yv; ssq[c] = fmaf(yv, yv, ssq[c]);
            if (r < 4) mx0[c] = fmaxf(mx0[c], yv);
            else       mx1[c] = fmaxf(mx1[c], yv);
        }
#pragma unroll
    for (int c = 0; c < 4; ++c) {
        atomicAdd(&sred[og2 * 4 + c], sum[c]);
        atomicAdd(&sred[128 + og2 * 4 + c], ssq[c]);
        maxbuf[0][pg2][og2 * 4 + c] = mx0[c];
        maxbuf[1][pg2][og2 * 4 + c] = mx1[c];
    }
    __syncthreads();
    {
        int cent2 = t >> 7, o = t & 127;
        float v = maxbuf[cent2][0][o];
#pragma unroll
        for (int q = 1; q < 8; ++q) v = fmaxf(v, maxbuf[cent2][q][o]);
        mout[(size_t)(blockIdx.x * 2 + cent2) * 128 + o] = v;
        atomicAdd(&stats2[t], sred[t]);
    }
}

// ======================= BN finalize =======================
__global__ void finalize_kernel(const float* __restrict__ stats, const float* __restrict__ g,
                                const float* __restrict__ beta, float* __restrict__ scl,
                                float* __restrict__ sh, int C)
{
    int c = threadIdx.x;
    if (c >= C) return;
    const float inv = 1.0f / 131072.0f;
    float mean = stats[c] * inv;
    float var  = stats[C + c] * inv - mean * mean;
    var = fmaxf(var, 0.f);
    float s = g[c] / sqrtf(var + 1e-5f);
    scl[c] = s;
    sh[c] = beta[c] - mean * s;
}

// ======================= writeout =======================
__global__ __launch_bounds__(256) void writeout_kernel(
    const float* __restrict__ m, const float* __restrict__ scl,
    const float* __restrict__ sh, float* __restrict__ out)
{
    int idx = blockIdx.x * 256 + threadIdx.x;
    int s = idx & 1023;
    int o = (idx >> 10) & 127;
    int b = idx >> 17;
    float v = m[(size_t)((b << 10) + s) * 128 + o];
    v = fmaxf(fmaf(v, scl[o], sh[o]), 0.f);
    out[idx] = v;
}

// ======================= launch =======================
extern "C" void kernel_launch(void* const* d_in, const int* in_sizes, int n_in,
                              void* d_out, int out_size, void* d_ws, size_t ws_size,
                              hipStream_t stream)
{
    const float* xyz = (const float*)d_in[0];
    const float* pts = (const float*)d_in[1];
    const float* W0  = (const float*)d_in[2];
    const float* b0  = (const float*)d_in[3];
    const float* g0  = (const float*)d_in[4];
    const float* be0 = (const float*)d_in[5];
    const float* W1  = (const float*)d_in[6];
    const float* b1  = (const float*)d_in[7];
    const float* g1  = (const float*)d_in[8];
    const float* be1 = (const float*)d_in[9];
    const float* W2  = (const float*)d_in[10];
    const float* b2  = (const float*)d_in[11];
    const float* g2  = (const float*)d_in[12];
    const float* be2 = (const float*)d_in[13];
    float* out = (float*)d_out;

    char* ws = (char*)d_ws;
    int*   fps_idx = (int*)(ws + 0);              // 16 KB
    int*   gi      = (int*)(ws + 16384);          // 512 KB -> ends 540672
    float* stats   = (float*)(ws + 540672);       // 512 f
    float* ss      = (float*)(ws + 542720);       // 512 f
    float* m       = (float*)(ws + 544768);       // 2 MB
    float* ptsT    = (float*)(ws + 2641920);      // 8 MB -> ends ~10.5 MB
    float *scl0 = ss, *sh0 = ss + 64, *scl1 = ss + 128, *sh1 = ss + 192,
          *scl2 = ss + 256, *sh2 = ss + 384;

    hipMemsetAsync(stats, 0, 2048, stream);

    hipLaunchKernelGGL(fps_kernel, dim3(4), dim3(512), 0, stream, xyz, fps_idx, out);
    hipLaunchKernelGGL(transpose_pts_kernel, dim3(128, 4), dim3(256), 0, stream, pts, ptsT);
    hipLaunchKernelGGL(ballq_kernel, dim3(1024), dim3(256), 0, stream, xyz, fps_idx, gi);
    hipLaunchKernelGGL(conv0_stats_kernel, dim3(1024), dim3(256), 0, stream,
                       xyz, ptsT, fps_idx, gi, W0, b0, stats);
    hipLaunchKernelGGL(finalize_kernel, dim3(1), dim3(64), 0, stream, stats, g0, be0, scl0, sh0, 64);
    hipLaunchKernelGGL(conv1_stats_kernel, dim3(2048), dim3(256), 0, stream,
                       xyz, ptsT, fps_idx, gi, W0, b0, W1, b1, scl0, sh0, stats + 128);
    hipLaunchKernelGGL(finalize_kernel, dim3(1), dim3(64), 0, stream, stats + 128, g1, be1, scl1, sh1, 64);
    hipLaunchKernelGGL(conv2_final_kernel, dim3(2048), dim3(256), 0, stream,
                       xyz, ptsT, fps_idx, gi, W0, b0, W1, b1, W2, b2,
                       scl0, sh0, scl1, sh1, m, stats + 256);
    hipLaunchKernelGGL(finalize_kernel, dim3(1), dim3(128), 0, stream, stats + 256, g2, be2, scl2, sh2, 128);
    hipLaunchKernelGGL(writeout_kernel, dim3(2048), dim3(256), 0, stream, m, scl2, sh2, out + 12288);
}

// Round 18
// 1544.575 us; speedup vs baseline: 1.5331x; 1.5003x over previous
//
#include <hip/hip_runtime.h>

#define N_PTS 8192
#define B_SZ 4
#define S_PTS 1024
#define K_SMP 32

// ======================= FPS =======================
// r17 post-mortem: coords remat'd from GLOBAL every iter (VGPR=60 < needed),
// per-CU L1/L2 BW-bound => TLP didn't help. Fix: stage xyz in 96KB dynamic
// LDS once; per-iter coord reads become conflict-free ds_read_b32 at LDS BW.
// Reduction cheapened to a single sortable u64 key:
//   key = (float_bits(dm) << 32) | (0xFFFFFFFF - idx)
// max-key == (greater value) OR (equal value AND lower index) — the exact
// reference tie-break (dm >= 0 so float bits are monotone). Distance chain
// unchanged (bit-exact). Single barrier/iter via parity double-buffer.
#define FPS_ALL(M) M(0) M(1) M(2) M(3) M(4) M(5) M(6) M(7) \
                   M(8) M(9) M(10) M(11) M(12) M(13) M(14) M(15)

#define FPS_DECL(J) float dmin##J = 1e10f;

#define FPS_STEP(J) { \
    float xx = lx[t + J*512], yy = ly[t + J*512], zz = lz[t + J*512]; \
    float dx = __fsub_rn(xx, cx); \
    float dy = __fsub_rn(yy, cy); \
    float dz = __fsub_rn(zz, cz); \
    float d  = __fadd_rn(__fadd_rn(__fmul_rn(dx, dx), __fmul_rn(dy, dy)), __fmul_rn(dz, dz)); \
    float dm = fminf(dmin##J, d); \
    dmin##J = dm; \
    unsigned long long key = ((unsigned long long)__float_as_uint(dm) << 32) \
                           | (unsigned)(0xFFFFFFFFu - (unsigned)(t + J*512)); \
    if (key > bestk) bestk = key; \
}

__global__ __launch_bounds__(512, 1) void fps_kernel(
    const float* __restrict__ xyz, int* __restrict__ fps_idx,
    float* __restrict__ out_newxyz)
{
    extern __shared__ float smem[];
    float* lx = smem;
    float* ly = smem + N_PTS;
    float* lz = smem + 2 * N_PTS;
    __shared__ unsigned long long wkey[2][8];   // [parity][wave]

    const int b = blockIdx.x;
    const int t = threadIdx.x;
    const int wave = t >> 6;
    const int lane = t & 63;
    const float* xb = xyz + (size_t)b * 3 * N_PTS;   // contiguous x|y|z

    // stage all of xyz into LDS (linear, coalesced)
    for (int i = t; i < 3 * N_PTS; i += 512) smem[i] = xb[i];
    __syncthreads();

    FPS_ALL(FPS_DECL)

    int far = 0;
    float cx = lx[0], cy = ly[0], cz = lz[0];

    for (int s = 0; s < S_PTS; ++s) {
        if (t == 0) {
            fps_idx[b * S_PTS + s] = far;
            out_newxyz[((size_t)b * 3 + 0) * S_PTS + s] = cx;
            out_newxyz[((size_t)b * 3 + 1) * S_PTS + s] = cy;
            out_newxyz[((size_t)b * 3 + 2) * S_PTS + s] = cz;
        }
        unsigned long long bestk = 0ull;
        FPS_ALL(FPS_STEP)

        // 64-lane butterfly max on the packed key
#pragma unroll
        for (int off = 32; off >= 1; off >>= 1) {
            unsigned long long ok = __shfl_xor(bestk, off, 64);
            if (ok > bestk) bestk = ok;
        }
        const int par = s & 1;
        if (lane == 0) wkey[par][wave] = bestk;
        __syncthreads();
#pragma unroll
        for (int w = 0; w < 8; ++w) {
            unsigned long long k2 = wkey[par][w];
            if (k2 > bestk) bestk = k2;
        }
        far = (int)(0xFFFFFFFFu - (unsigned)bestk);
        cx = lx[far]; cy = ly[far]; cz = lz[far];
    }
}

// ======================= points transpose (B,D,N) -> (B,N,D) =======================
__global__ __launch_bounds__(256) void transpose_pts_kernel(
    const float* __restrict__ pts, float* __restrict__ ptsT)
{
    __shared__ float T[64][65];
    const int b  = blockIdx.y;
    const int n0 = blockIdx.x * 64;
    const int t  = threadIdx.x;
    const int c  = t & 63;
    const int r0 = (t >> 6) * 16;
#pragma unroll
    for (int rr = 0; rr < 16; ++rr) {
        int d = r0 + rr;
        T[d][c] = pts[((size_t)b * 64 + d) * N_PTS + n0 + c];
    }
    __syncthreads();
#pragma unroll
    for (int rr = 0; rr < 16; ++rr) {
        int n = r0 + rr;
        ptsT[((size_t)b * N_PTS + n0 + n) * 64 + c] = T[c][n];
    }
}

// ======================= ball query ======================= [verified pass r14-r17]
// Association (c): sqr = rn( rn(-2*dot + ps) + cs ), ascNoFMA dot.
__global__ __launch_bounds__(256) void ballq_kernel(
    const float* __restrict__ xyz, const int* __restrict__ fps_idx,
    int* __restrict__ gi)
{
    const int gw   = (blockIdx.x * 256 + threadIdx.x) >> 6;
    const int lane = threadIdx.x & 63;
    const int b = gw >> 10;
    const float* xs = xyz + (size_t)b * 3 * N_PTS;
    const float* ys = xs + N_PTS;
    const float* zs = ys + N_PTS;

    const int fi = fps_idx[gw];
    const float cx = xs[fi], cy = ys[fi], cz = zs[fi];
    const float cs = __fadd_rn(__fadd_rn(__fmul_rn(cx, cx), __fmul_rn(cy, cy)), __fmul_rn(cz, cz));

    int cnt = 0, myidx = 0, firstIdx = 0;
    for (int base = 0; base < N_PTS && cnt < K_SMP; base += 64) {
        int p = base + lane;
        float xx = xs[p], yy = ys[p], zz = zs[p];
        float dot = __fadd_rn(__fadd_rn(__fmul_rn(cx, xx), __fmul_rn(cy, yy)), __fmul_rn(cz, zz));
        float ps  = __fadd_rn(__fadd_rn(__fmul_rn(xx, xx), __fmul_rn(yy, yy)), __fmul_rn(zz, zz));
        float sqr = __fadd_rn(__fadd_rn(__fmul_rn(-2.0f, dot), ps), cs);   // (c)
        bool valid = !(sqr > 0.01f);
        unsigned long long mask = __ballot(valid);
        while (mask && cnt < K_SMP) {
            int bpos = __ffsll((long long)mask) - 1;
            mask &= mask - 1;
            if (cnt == lane) myidx = base + bpos;
            if (cnt == 0)    firstIdx = base + bpos;
            cnt++;
        }
    }
    if (lane < K_SMP) {
        if (lane >= cnt) myidx = firstIdx;
        gi[(size_t)gw * K_SMP + lane] = myidx;
    }
}

// ======================= K1: layer-0 stats only (no y store) =======================
__global__ __launch_bounds__(256) void conv0_stats_kernel(
    const float* __restrict__ xyz, const float* __restrict__ ptsT,
    const int* __restrict__ fps_idx, const int* __restrict__ gi,
    const float* __restrict__ W0, const float* __restrict__ bias0,
    float* __restrict__ stats0)
{
    __shared__ float A[128 * 68];
    __shared__ float Wt[68 * 64];
    __shared__ float cent[4][3];
    __shared__ float bsh[64];
    __shared__ float sred[128];

    const int t = threadIdx.x;
    const size_t pos0 = (size_t)blockIdx.x * 128;
    const int b  = (int)(pos0 >> 15);
    const int s0 = (int)((pos0 >> 5) & (S_PTS - 1));
    const float* xs = xyz + (size_t)b * 3 * N_PTS;
    const float* ys = xs + N_PTS;
    const float* zs = ys + N_PTS;

    if (t < 4) {
        int fi = fps_idx[b * S_PTS + s0 + t];
        cent[t][0] = xs[fi]; cent[t][1] = ys[fi]; cent[t][2] = zs[fi];
    }
    if (t >= 128 && t < 192) bsh[t - 128] = bias0[t - 128];
    if (t >= 192) { sred[t - 192] = 0.f; sred[t - 128] = 0.f; }
    for (int i = t; i < 68 * 64; i += 256) {
        int c = i >> 6, o = i & 63;
        float v = 0.f;
        if (c < 64) v = W0[o * 67 + 3 + c];
        else if (c < 67) v = W0[o * 67 + (c - 64)];
        Wt[i] = v;
    }
    for (int i = t; i < 128 * 16; i += 256) {
        int pos = i >> 4, j = i & 15;
        float4 v = *(const float4*)(ptsT + ((size_t)b * N_PTS + gi[pos0 + pos]) * 64 + j * 4);
        *(float4*)(A + pos * 68 + j * 4) = v;
    }
    __syncthreads();
    if (t < 128) {
        int g = gi[pos0 + t]; int ci = t >> 5;
        A[t * 68 + 64] = __fsub_rn(xs[g], cent[ci][0]);
        A[t * 68 + 65] = __fsub_rn(ys[g], cent[ci][1]);
        A[t * 68 + 66] = __fsub_rn(zs[g], cent[ci][2]);
        A[t * 68 + 67] = 0.f;
    }
    __syncthreads();

    const int og = t & 15;
    const int pg = t >> 4;
    float acc[8][4];
#pragma unroll
    for (int r = 0; r < 8; ++r)
#pragma unroll
        for (int c = 0; c < 4; ++c) acc[r][c] = 0.f;

    for (int j = 0; j < 17; ++j) {
        float w[4][4];
#pragma unroll
        for (int cc = 0; cc < 4; ++cc) {
            float4 v = *(const float4*)(Wt + (j * 4 + cc) * 64 + og * 4);
            w[cc][0] = v.x; w[cc][1] = v.y; w[cc][2] = v.z; w[cc][3] = v.w;
        }
#pragma unroll
        for (int r = 0; r < 8; ++r) {
            float4 v = *(const float4*)(A + (pg + r * 16) * 68 + j * 4);
#pragma unroll
            for (int co = 0; co < 4; ++co) {
                float s = acc[r][co];
                s = fmaf(v.x, w[0][co], s);
                s = fmaf(v.y, w[1][co], s);
                s = fmaf(v.z, w[2][co], s);
                s = fmaf(v.w, w[3][co], s);
                acc[r][co] = s;
            }
        }
    }

    float sum[4] = {0,0,0,0}, ssq[4] = {0,0,0,0};
#pragma unroll
    for (int r = 0; r < 8; ++r)
#pragma unroll
        for (int c = 0; c < 4; ++c) {
            float yv = acc[r][c] + bsh[og * 4 + c];
            sum[c] += yv; ssq[c] = fmaf(yv, yv, ssq[c]);
        }
#pragma unroll
    for (int c = 0; c < 4; ++c) {
        atomicAdd(&sred[og * 4 + c], sum[c]);
        atomicAdd(&sred[64 + og * 4 + c], ssq[c]);
    }
    __syncthreads();
    if (t < 128) atomicAdd(&stats0[t], sred[t]);
}

// ======================= K2: recompute mm0 -> BN0 -> mm1, layer-1 stats =======================
__global__ __launch_bounds__(256) void conv1_stats_kernel(
    const float* __restrict__ xyz, const float* __restrict__ ptsT,
    const int* __restrict__ fps_idx, const int* __restrict__ gi,
    const float* __restrict__ W0, const float* __restrict__ bias0,
    const float* __restrict__ W1, const float* __restrict__ bias1,
    const float* __restrict__ scl0, const float* __restrict__ sh0,
    float* __restrict__ stats1)
{
    __shared__ float A[64 * 68];
    __shared__ float W0t[68 * 64];
    __shared__ float W1t[64 * 64];
    __shared__ float cent[2][3];
    __shared__ float b0sh[64], b1sh[64], s0sh[64], h0sh[64];
    __shared__ float sred[128];

    const int t = threadIdx.x;
    const size_t pos0 = (size_t)blockIdx.x * 64;
    const int b  = (int)(pos0 >> 15);
    const int s0 = (int)((pos0 >> 5) & (S_PTS - 1));
    const float* xs = xyz + (size_t)b * 3 * N_PTS;
    const float* ys = xs + N_PTS;
    const float* zs = ys + N_PTS;

    if (t < 2) {
        int fi = fps_idx[b * S_PTS + s0 + t];
        cent[t][0] = xs[fi]; cent[t][1] = ys[fi]; cent[t][2] = zs[fi];
    }
    if (t >= 64 && t < 128) { b0sh[t-64] = bias0[t-64]; b1sh[t-64] = bias1[t-64]; }
    if (t >= 128 && t < 192) { s0sh[t-128] = scl0[t-128]; h0sh[t-128] = sh0[t-128]; }
    if (t >= 192) { sred[t-192] = 0.f; sred[t-128] = 0.f; }
    for (int i = t; i < 68 * 64; i += 256) {
        int c = i >> 6, o = i & 63;
        float v = 0.f;
        if (c < 64) v = W0[o * 67 + 3 + c];
        else if (c < 67) v = W0[o * 67 + (c - 64)];
        W0t[i] = v;
    }
    for (int i = t; i < 64 * 64; i += 256) { int c = i >> 6, o = i & 63; W1t[i] = W1[o * 64 + c]; }
    for (int i = t; i < 64 * 16; i += 256) {
        int pos = i >> 4, j = i & 15;
        float4 v = *(const float4*)(ptsT + ((size_t)b * N_PTS + gi[pos0 + pos]) * 64 + j * 4);
        *(float4*)(A + pos * 68 + j * 4) = v;
    }
    __syncthreads();
    if (t < 64) {
        int g = gi[pos0 + t]; int ci = t >> 5;
        A[t * 68 + 64] = __fsub_rn(xs[g], cent[ci][0]);
        A[t * 68 + 65] = __fsub_rn(ys[g], cent[ci][1]);
        A[t * 68 + 66] = __fsub_rn(zs[g], cent[ci][2]);
        A[t * 68 + 67] = 0.f;
    }
    __syncthreads();

    const int og = t & 15;
    const int pg = t >> 4;
    float acc[4][4];
#pragma unroll
    for (int r = 0; r < 4; ++r)
#pragma unroll
        for (int c = 0; c < 4; ++c) acc[r][c] = 0.f;

    for (int j = 0; j < 17; ++j) {
        float w[4][4];
#pragma unroll
        for (int cc = 0; cc < 4; ++cc) {
            float4 v = *(const float4*)(W0t + (j * 4 + cc) * 64 + og * 4);
            w[cc][0] = v.x; w[cc][1] = v.y; w[cc][2] = v.z; w[cc][3] = v.w;
        }
#pragma unroll
        for (int r = 0; r < 4; ++r) {
            float4 v = *(const float4*)(A + (pg + r * 16) * 68 + j * 4);
#pragma unroll
            for (int co = 0; co < 4; ++co) {
                float s = acc[r][co];
                s = fmaf(v.x, w[0][co], s);
                s = fmaf(v.y, w[1][co], s);
                s = fmaf(v.z, w[2][co], s);
                s = fmaf(v.w, w[3][co], s);
                acc[r][co] = s;
            }
        }
    }
    __syncthreads();
#pragma unroll
    for (int r = 0; r < 4; ++r) {
        float4 z;
        z.x = fmaxf(fmaf(acc[r][0] + b0sh[og*4+0], s0sh[og*4+0], h0sh[og*4+0]), 0.f);
        z.y = fmaxf(fmaf(acc[r][1] + b0sh[og*4+1], s0sh[og*4+1], h0sh[og*4+1]), 0.f);
        z.z = fmaxf(fmaf(acc[r][2] + b0sh[og*4+2], s0sh[og*4+2], h0sh[og*4+2]), 0.f);
        z.w = fmaxf(fmaf(acc[r][3] + b0sh[og*4+3], s0sh[og*4+3], h0sh[og*4+3]), 0.f);
        *(float4*)(A + (pg + r * 16) * 68 + og * 4) = z;
    }
    __syncthreads();
    float acc1[4][4];
#pragma unroll
    for (int r = 0; r < 4; ++r)
#pragma unroll
        for (int c = 0; c < 4; ++c) acc1[r][c] = 0.f;
    for (int j = 0; j < 16; ++j) {
        float w[4][4];
#pragma unroll
        for (int cc = 0; cc < 4; ++cc) {
            float4 v = *(const float4*)(W1t + (j * 4 + cc) * 64 + og * 4);
            w[cc][0] = v.x; w[cc][1] = v.y; w[cc][2] = v.z; w[cc][3] = v.w;
        }
#pragma unroll
        for (int r = 0; r < 4; ++r) {
            float4 v = *(const float4*)(A + (pg + r * 16) * 68 + j * 4);
#pragma unroll
            for (int co = 0; co < 4; ++co) {
                float s = acc1[r][co];
                s = fmaf(v.x, w[0][co], s);
                s = fmaf(v.y, w[1][co], s);
                s = fmaf(v.z, w[2][co], s);
                s = fmaf(v.w, w[3][co], s);
                acc1[r][co] = s;
            }
        }
    }
    float sum[4] = {0,0,0,0}, ssq[4] = {0,0,0,0};
#pragma unroll
    for (int r = 0; r < 4; ++r)
#pragma unroll
        for (int c = 0; c < 4; ++c) {
            float yv = acc1[r][c] + b1sh[og * 4 + c];
            sum[c] += yv; ssq[c] = fmaf(yv, yv, ssq[c]);
        }
#pragma unroll
    for (int c = 0; c < 4; ++c) {
        atomicAdd(&sred[og * 4 + c], sum[c]);
        atomicAdd(&sred[64 + og * 4 + c], ssq[c]);
    }
    __syncthreads();
    if (t < 128) atomicAdd(&stats1[t], sred[t]);
}

// ======================= K3: full chain -> layer-2 stats + K-max =======================
__global__ __launch_bounds__(256) void conv2_final_kernel(
    const float* __restrict__ xyz, const float* __restrict__ ptsT,
    const int* __restrict__ fps_idx, const int* __restrict__ gi,
    const float* __restrict__ W0, const float* __restrict__ bias0,
    const float* __restrict__ W1, const float* __restrict__ bias1,
    const float* __restrict__ W2, const float* __restrict__ bias2,
    const float* __restrict__ scl0, const float* __restrict__ sh0,
    const float* __restrict__ scl1, const float* __restrict__ sh1,
    float* __restrict__ mout, float* __restrict__ stats2)
{
    __shared__ float A[64 * 68];
    __shared__ float Wb[8192];
    __shared__ float cent[2][3];
    __shared__ float b0sh[64], b1sh[64], b2sh[128];
    __shared__ float s0sh[64], h0sh[64], s1sh[64], h1sh[64];
    __shared__ float sred[256];
    __shared__ float maxbuf[2][8][128];

    const int t = threadIdx.x;
    const size_t pos0 = (size_t)blockIdx.x * 64;
    const int b  = (int)(pos0 >> 15);
    const int s0 = (int)((pos0 >> 5) & (S_PTS - 1));
    const float* xs = xyz + (size_t)b * 3 * N_PTS;
    const float* ys = xs + N_PTS;
    const float* zs = ys + N_PTS;

    if (t < 2) {
        int fi = fps_idx[b * S_PTS + s0 + t];
        cent[t][0] = xs[fi]; cent[t][1] = ys[fi]; cent[t][2] = zs[fi];
    }
    if (t < 64) { s0sh[t] = scl0[t]; h0sh[t] = sh0[t]; }
    else if (t < 128) { s1sh[t-64] = scl1[t-64]; h1sh[t-64] = sh1[t-64]; }
    else if (t < 192) { b0sh[t-128] = bias0[t-128]; b1sh[t-128] = bias1[t-128]; }
    else { int q = (t - 192) * 4; sred[q]=0.f; sred[q+1]=0.f; sred[q+2]=0.f; sred[q+3]=0.f; }
    if (t < 128) b2sh[t] = bias2[t];
    for (int i = t; i < 68 * 64; i += 256) {
        int c = i >> 6, o = i & 63;
        float v = 0.f;
        if (c < 64) v = W0[o * 67 + 3 + c];
        else if (c < 67) v = W0[o * 67 + (c - 64)];
        Wb[i] = v;
    }
    for (int i = t; i < 64 * 16; i += 256) {
        int pos = i >> 4, j = i & 15;
        float4 v = *(const float4*)(ptsT + ((size_t)b * N_PTS + gi[pos0 + pos]) * 64 + j * 4);
        *(float4*)(A + pos * 68 + j * 4) = v;
    }
    __syncthreads();
    if (t < 64) {
        int g = gi[pos0 + t]; int ci = t >> 5;
        A[t * 68 + 64] = __fsub_rn(xs[g], cent[ci][0]);
        A[t * 68 + 65] = __fsub_rn(ys[g], cent[ci][1]);
        A[t * 68 + 66] = __fsub_rn(zs[g], cent[ci][2]);
        A[t * 68 + 67] = 0.f;
    }
    __syncthreads();

    const int og = t & 15;
    const int pg = t >> 4;
    float acc[4][4];
#pragma unroll
    for (int r = 0; r < 4; ++r)
#pragma unroll
        for (int c = 0; c < 4; ++c) acc[r][c] = 0.f;
    for (int j = 0; j < 17; ++j) {
        float w[4][4];
#pragma unroll
        for (int cc = 0; cc < 4; ++cc) {
            float4 v = *(const float4*)(Wb + (j * 4 + cc) * 64 + og * 4);
            w[cc][0] = v.x; w[cc][1] = v.y; w[cc][2] = v.z; w[cc][3] = v.w;
        }
#pragma unroll
        for (int r = 0; r < 4; ++r) {
            float4 v = *(const float4*)(A + (pg + r * 16) * 68 + j * 4);
#pragma unroll
            for (int co = 0; co < 4; ++co) {
                float s = acc[r][co];
                s = fmaf(v.x, w[0][co], s);
                s = fmaf(v.y, w[1][co], s);
                s = fmaf(v.z, w[2][co], s);
                s = fmaf(v.w, w[3][co], s);
                acc[r][co] = s;
            }
        }
    }
    __syncthreads();
#pragma unroll
    for (int r = 0; r < 4; ++r) {
        float4 z;
        z.x = fmaxf(fmaf(acc[r][0] + b0sh[og*4+0], s0sh[og*4+0], h0sh[og*4+0]), 0.f);
        z.y = fmaxf(fmaf(acc[r][1] + b0sh[og*4+1], s0sh[og*4+1], h0sh[og*4+1]), 0.f);
        z.z = fmaxf(fmaf(acc[r][2] + b0sh[og*4+2], s0sh[og*4+2], h0sh[og*4+2]), 0.f);
        z.w = fmaxf(fmaf(acc[r][3] + b0sh[og*4+3], s0sh[og*4+3], h0sh[og*4+3]), 0.f);
        *(float4*)(A + (pg + r * 16) * 68 + og * 4) = z;
    }
    for (int i = t; i < 64 * 64; i += 256) { int c = i >> 6, o = i & 63; Wb[i] = W1[o * 64 + c]; }
    __syncthreads();
    float acc1[4][4];
#pragma unroll
    for (int r = 0; r < 4; ++r)
#pragma unroll
        for (int c = 0; c < 4; ++c) acc1[r][c] = 0.f;
    for (int j = 0; j < 16; ++j) {
        float w[4][4];
#pragma unroll
        for (int cc = 0; cc < 4; ++cc) {
            float4 v = *(const float4*)(Wb + (j * 4 + cc) * 64 + og * 4);
            w[cc][0] = v.x; w[cc][1] = v.y; w[cc][2] = v.z; w[cc][3] = v.w;
        }
#pragma unroll
        for (int r = 0; r < 4; ++r) {
            float4 v = *(const float4*)(A + (pg + r * 16) * 68 + j * 4);
#pragma unroll
            for (int co = 0; co < 4; ++co) {
                float s = acc1[r][co];
                s = fmaf(v.x, w[0][co], s);
                s = fmaf(v.y, w[1][co], s);
                s = fmaf(v.z, w[2][co], s);
                s = fmaf(v.w, w[3][co], s);
                acc1[r][co] = s;
            }
        }
    }
    __syncthreads();
#pragma unroll
    for (int r = 0; r < 4; ++r) {
        float4 z;
        z.x = fmaxf(fmaf(acc1[r][0] + b1sh[og*4+0], s1sh[og*4+0], h1sh[og*4+0]), 0.f);
        z.y = fmaxf(fmaf(acc1[r][1] + b1sh[og*4+1], s1sh[og*4+1], h1sh[og*4+1]), 0.f);
        z.z = fmaxf(fmaf(acc1[r][2] + b1sh[og*4+2], s1sh[og*4+2], h1sh[og*4+2]), 0.f);
        z.w = fmaxf(fmaf(acc1[r][3] + b1sh[og*4+3], s1sh[og*4+3], h1sh[og*4+3]), 0.f);
        *(float4*)(A + (pg + r * 16) * 68 + og * 4) = z;
    }
    for (int i = t; i < 64 * 128; i += 256) { int c = i >> 7, o = i & 127; Wb[i] = W2[o * 64 + c]; }
    __syncthreads();
    const int og2 = t & 31;
    const int pg2 = t >> 5;
    float acc2[8][4];
#pragma unroll
    for (int r = 0; r < 8; ++r)
#pragma unroll
        for (int c = 0; c < 4; ++c) acc2[r][c] = 0.f;
    for (int j = 0; j < 16; ++j) {
        float w[4][4];
#pragma unroll
        for (int cc = 0; cc < 4; ++cc) {
            float4 v = *(const float4*)(Wb + (j * 4 + cc) * 128 + og2 * 4);
            w[cc][0] = v.x; w[cc][1] = v.y; w[cc][2] = v.z; w[cc][3] = v.w;
        }
#pragma unroll
        for (int r = 0; r < 8; ++r) {
            float4 v = *(const float4*)(A + (pg2 + r * 8) * 68 + j * 4);
#pragma unroll
            for (int co = 0; co < 4; ++co) {
                float s = acc2[r][co];
                s = fmaf(v.x, w[0][co], s);
                s = fmaf(v.y, w[1][co], s);
                s = fmaf(v.z, w[2][co], s);
                s = fmaf(v.w, w[3][co], s);
                acc2[r][co] = s;
            }
        }
    }
    float sum[4] = {0,0,0,0}, ssq[4] = {0,0,0,0};
    float mx0[4], mx1[4];
#pragma unroll
    for (int c = 0; c < 4; ++c) { mx0[c] = -3.402823466e38f; mx1[c] = -3.402823466e38f; }
#pragma unroll
    for (int r = 0; r < 8; ++r)
#pragma unroll
        for (int c = 0; c < 4; ++c) {
            float yv = acc2[r][c] + b2sh[og2 * 4 + c];
            sum[c] += yv; ssq[c] = fmaf(yv, yv, ssq[c]);
            if (r < 4) mx0[c] = fmaxf(mx0[c], yv);
            else       mx1[c] = fmaxf(mx1[c], yv);
        }
#pragma unroll
    for (int c = 0; c < 4; ++c) {
        atomicAdd(&sred[og2 * 4 + c], sum[c]);
        atomicAdd(&sred[128 + og2 * 4 + c], ssq[c]);
        maxbuf[0][pg2][og2 * 4 + c] = mx0[c];
        maxbuf[1][pg2][og2 * 4 + c] = mx1[c];
    }
    __syncthreads();
    {
        int cent2 = t >> 7, o = t & 127;
        float v = maxbuf[cent2][0][o];
#pragma unroll
        for (int q = 1; q < 8; ++q) v = fmaxf(v, maxbuf[cent2][q][o]);
        mout[(size_t)(blockIdx.x * 2 + cent2) * 128 + o] = v;
        atomicAdd(&stats2[t], sred[t]);
    }
}

// ======================= BN finalize =======================
__global__ void finalize_kernel(const float* __restrict__ stats, const float* __restrict__ g,
                                const float* __restrict__ beta, float* __restrict__ scl,
                                float* __restrict__ sh, int C)
{
    int c = threadIdx.x;
    if (c >= C) return;
    const float inv = 1.0f / 131072.0f;
    float mean = stats[c] * inv;
    float var  = stats[C + c] * inv - mean * mean;
    var = fmaxf(var, 0.f);
    float s = g[c] / sqrtf(var + 1e-5f);
    scl[c] = s;
    sh[c] = beta[c] - mean * s;
}

// ======================= writeout =======================
__global__ __launch_bounds__(256) void writeout_kernel(
    const float* __restrict__ m, const float* __restrict__ scl,
    const float* __restrict__ sh, float* __restrict__ out)
{
    int idx = blockIdx.x * 256 + threadIdx.x;
    int s = idx & 1023;
    int o = (idx >> 10) & 127;
    int b = idx >> 17;
    float v = m[(size_t)((b << 10) + s) * 128 + o];
    v = fmaxf(fmaf(v, scl[o], sh[o]), 0.f);
    out[idx] = v;
}

// ======================= launch =======================
extern "C" void kernel_launch(void* const* d_in, const int* in_sizes, int n_in,
                              void* d_out, int out_size, void* d_ws, size_t ws_size,
                              hipStream_t stream)
{
    const float* xyz = (const float*)d_in[0];
    const float* pts = (const float*)d_in[1];
    const float* W0  = (const float*)d_in[2];
    const float* b0  = (const float*)d_in[3];
    const float* g0  = (const float*)d_in[4];
    const float* be0 = (const float*)d_in[5];
    const float* W1  = (const float*)d_in[6];
    const float* b1  = (const float*)d_in[7];
    const float* g1  = (const float*)d_in[8];
    const float* be1 = (const float*)d_in[9];
    const float* W2  = (const float*)d_in[10];
    const float* b2  = (const float*)d_in[11];
    const float* g2  = (const float*)d_in[12];
    const float* be2 = (const float*)d_in[13];
    float* out = (float*)d_out;

    char* ws = (char*)d_ws;
    int*   fps_idx = (int*)(ws + 0);              // 16 KB
    int*   gi      = (int*)(ws + 16384);          // 512 KB -> ends 540672
    float* stats   = (float*)(ws + 540672);       // 512 f
    float* ss      = (float*)(ws + 542720);       // 512 f
    float* m       = (float*)(ws + 544768);       // 2 MB
    float* ptsT    = (float*)(ws + 2641920);      // 8 MB -> ends ~10.5 MB
    float *scl0 = ss, *sh0 = ss + 64, *scl1 = ss + 128, *sh1 = ss + 192,
          *scl2 = ss + 256, *sh2 = ss + 384;

    hipMemsetAsync(stats, 0, 2048, stream);

    hipFuncSetAttribute((const void*)fps_kernel,
                        hipFuncAttributeMaxDynamicSharedMemorySize, 3 * N_PTS * 4);
    hipLaunchKernelGGL(fps_kernel, dim3(4), dim3(512), 3 * N_PTS * 4, stream,
                       xyz, fps_idx, out);
    hipLaunchKernelGGL(transpose_pts_kernel, dim3(128, 4), dim3(256), 0, stream, pts, ptsT);
    hipLaunchKernelGGL(ballq_kernel, dim3(1024), dim3(256), 0, stream, xyz, fps_idx, gi);
    hipLaunchKernelGGL(conv0_stats_kernel, dim3(1024), dim3(256), 0, stream,
                       xyz, ptsT, fps_idx, gi, W0, b0, stats);
    hipLaunchKernelGGL(finalize_kernel, dim3(1), dim3(64), 0, stream, stats, g0, be0, scl0, sh0, 64);
    hipLaunchKernelGGL(conv1_stats_kernel, dim3(2048), dim3(256), 0, stream,
                       xyz, ptsT, fps_idx, gi, W0, b0, W1, b1, scl0, sh0, stats + 128);
    hipLaunchKernelGGL(finalize_kernel, dim3(1), dim3(64), 0, stream, stats + 128, g1, be1, scl1, sh1, 64);
    hipLaunchKernelGGL(conv2_final_kernel, dim3(2048), dim3(256), 0, stream,
                       xyz, ptsT, fps_idx, gi, W0, b0, W1, b1, W2, b2,
                       scl0, sh0, scl1, sh1, m, stats + 256);
    hipLaunchKernelGGL(finalize_kernel, dim3(1), dim3(128), 0, stream, stats + 256, g2, be2, scl2, sh2, 128);
    hipLaunchKernelGGL(writeout_kernel, dim3(2048), dim3(256), 0, stream, m, scl2, sh2, out + 12288);
}

// Round 19
// 1476.418 us; speedup vs baseline: 1.6038x; 1.0462x over previous
//
#include <hip/hip_runtime.h>

#define N_PTS 8192
#define B_SZ 4
#define S_PTS 1024
#define K_SMP 32

// ======================= FPS =======================
// r18: LDS staging fixed the global-remat wall (2015->1216us) but the DS pipe
// is now the bottleneck: 48 ds_read_b32/thread/iter = 384 wave-instrs/CU/iter
// x 5.8cyc = 2230cyc. Fix: pack points as float4[8192] (x,y,z,pad; 128KiB) so
// each point is ONE ds_read_b128 (consecutive 16B/lane = conflict-free wide
// pattern, ~12cyc/instr) -> 128 wave-instrs/CU/iter = 1536cyc.
// Same bits, same distance chain, same u64-key reduce (value desc, index asc)
// => bit-exact vs r14-r18.
#define FPS_ALL(M) M(0) M(1) M(2) M(3) M(4) M(5) M(6) M(7) \
                   M(8) M(9) M(10) M(11) M(12) M(13) M(14) M(15)

#define FPS_DECL(J) float dmin##J = 1e10f;

#define FPS_STEP(J) { \
    float4 p = lds4[t + J*512]; \
    float dx = __fsub_rn(p.x, cx); \
    float dy = __fsub_rn(p.y, cy); \
    float dz = __fsub_rn(p.z, cz); \
    float d  = __fadd_rn(__fadd_rn(__fmul_rn(dx, dx), __fmul_rn(dy, dy)), __fmul_rn(dz, dz)); \
    float dm = fminf(dmin##J, d); \
    dmin##J = dm; \
    unsigned long long key = ((unsigned long long)__float_as_uint(dm) << 32) \
                           | (unsigned)(0xFFFFFFFFu - (unsigned)(t + J*512)); \
    if (key > bestk) bestk = key; \
}

__global__ __launch_bounds__(512, 1) void fps_kernel(
    const float* __restrict__ xyz, int* __restrict__ fps_idx,
    float* __restrict__ out_newxyz)
{
    extern __shared__ float4 lds4[];
    __shared__ unsigned long long wkey[2][8];   // [parity][wave]

    const int b = blockIdx.x;
    const int t = threadIdx.x;
    const int wave = t >> 6;
    const int lane = t & 63;
    const float* xs = xyz + (size_t)b * 3 * N_PTS;
    const float* ys = xs + N_PTS;
    const float* zs = ys + N_PTS;

    // stage xyz into interleaved float4 LDS (reads coalesced per array)
    for (int i = t; i < N_PTS; i += 512) {
        float4 p; p.x = xs[i]; p.y = ys[i]; p.z = zs[i]; p.w = 0.f;
        lds4[i] = p;
    }
    __syncthreads();

    FPS_ALL(FPS_DECL)

    int far = 0;
    float4 c0 = lds4[0];
    float cx = c0.x, cy = c0.y, cz = c0.z;

    for (int s = 0; s < S_PTS; ++s) {
        if (t == 0) {
            fps_idx[b * S_PTS + s] = far;
            out_newxyz[((size_t)b * 3 + 0) * S_PTS + s] = cx;
            out_newxyz[((size_t)b * 3 + 1) * S_PTS + s] = cy;
            out_newxyz[((size_t)b * 3 + 2) * S_PTS + s] = cz;
        }
        unsigned long long bestk = 0ull;
        FPS_ALL(FPS_STEP)

        // 64-lane butterfly max on the packed key
#pragma unroll
        for (int off = 32; off >= 1; off >>= 1) {
            unsigned long long ok = __shfl_xor(bestk, off, 64);
            if (ok > bestk) bestk = ok;
        }
        const int par = s & 1;
        if (lane == 0) wkey[par][wave] = bestk;
        __syncthreads();
#pragma unroll
        for (int w = 0; w < 8; ++w) {
            unsigned long long k2 = wkey[par][w];
            if (k2 > bestk) bestk = k2;
        }
        far = (int)(0xFFFFFFFFu - (unsigned)bestk);
        float4 c = lds4[far];
        cx = c.x; cy = c.y; cz = c.z;
    }
}

// ======================= points transpose (B,D,N) -> (B,N,D) =======================
__global__ __launch_bounds__(256) void transpose_pts_kernel(
    const float* __restrict__ pts, float* __restrict__ ptsT)
{
    __shared__ float T[64][65];
    const int b  = blockIdx.y;
    const int n0 = blockIdx.x * 64;
    const int t  = threadIdx.x;
    const int c  = t & 63;
    const int r0 = (t >> 6) * 16;
#pragma unroll
    for (int rr = 0; rr < 16; ++rr) {
        int d = r0 + rr;
        T[d][c] = pts[((size_t)b * 64 + d) * N_PTS + n0 + c];
    }
    __syncthreads();
#pragma unroll
    for (int rr = 0; rr < 16; ++rr) {
        int n = r0 + rr;
        ptsT[((size_t)b * N_PTS + n0 + n) * 64 + c] = T[c][n];
    }
}

// ======================= ball query ======================= [verified pass r14-r18]
// Association (c): sqr = rn( rn(-2*dot + ps) + cs ), ascNoFMA dot.
__global__ __launch_bounds__(256) void ballq_kernel(
    const float* __restrict__ xyz, const int* __restrict__ fps_idx,
    int* __restrict__ gi)
{
    const int gw   = (blockIdx.x * 256 + threadIdx.x) >> 6;
    const int lane = threadIdx.x & 63;
    const int b = gw >> 10;
    const float* xs = xyz + (size_t)b * 3 * N_PTS;
    const float* ys = xs + N_PTS;
    const float* zs = ys + N_PTS;

    const int fi = fps_idx[gw];
    const float cx = xs[fi], cy = ys[fi], cz = zs[fi];
    const float cs = __fadd_rn(__fadd_rn(__fmul_rn(cx, cx), __fmul_rn(cy, cy)), __fmul_rn(cz, cz));

    int cnt = 0, myidx = 0, firstIdx = 0;
    for (int base = 0; base < N_PTS && cnt < K_SMP; base += 64) {
        int p = base + lane;
        float xx = xs[p], yy = ys[p], zz = zs[p];
        float dot = __fadd_rn(__fadd_rn(__fmul_rn(cx, xx), __fmul_rn(cy, yy)), __fmul_rn(cz, zz));
        float ps  = __fadd_rn(__fadd_rn(__fmul_rn(xx, xx), __fmul_rn(yy, yy)), __fmul_rn(zz, zz));
        float sqr = __fadd_rn(__fadd_rn(__fmul_rn(-2.0f, dot), ps), cs);   // (c)
        bool valid = !(sqr > 0.01f);
        unsigned long long mask = __ballot(valid);
        while (mask && cnt < K_SMP) {
            int bpos = __ffsll((long long)mask) - 1;
            mask &= mask - 1;
            if (cnt == lane) myidx = base + bpos;
            if (cnt == 0)    firstIdx = base + bpos;
            cnt++;
        }
    }
    if (lane < K_SMP) {
        if (lane >= cnt) myidx = firstIdx;
        gi[(size_t)gw * K_SMP + lane] = myidx;
    }
}

// ======================= K1: layer-0 stats only (no y store) =======================
__global__ __launch_bounds__(256) void conv0_stats_kernel(
    const float* __restrict__ xyz, const float* __restrict__ ptsT,
    const int* __restrict__ fps_idx, const int* __restrict__ gi,
    const float* __restrict__ W0, const float* __restrict__ bias0,
    float* __restrict__ stats0)
{
    __shared__ float A[128 * 68];
    __shared__ float Wt[68 * 64];
    __shared__ float cent[4][3];
    __shared__ float bsh[64];
    __shared__ float sred[128];

    const int t = threadIdx.x;
    const size_t pos0 = (size_t)blockIdx.x * 128;
    const int b  = (int)(pos0 >> 15);
    const int s0 = (int)((pos0 >> 5) & (S_PTS - 1));
    const float* xs = xyz + (size_t)b * 3 * N_PTS;
    const float* ys = xs + N_PTS;
    const float* zs = ys + N_PTS;

    if (t < 4) {
        int fi = fps_idx[b * S_PTS + s0 + t];
        cent[t][0] = xs[fi]; cent[t][1] = ys[fi]; cent[t][2] = zs[fi];
    }
    if (t >= 128 && t < 192) bsh[t - 128] = bias0[t - 128];
    if (t >= 192) { sred[t - 192] = 0.f; sred[t - 128] = 0.f; }
    for (int i = t; i < 68 * 64; i += 256) {
        int c = i >> 6, o = i & 63;
        float v = 0.f;
        if (c < 64) v = W0[o * 67 + 3 + c];
        else if (c < 67) v = W0[o * 67 + (c - 64)];
        Wt[i] = v;
    }
    for (int i = t; i < 128 * 16; i += 256) {
        int pos = i >> 4, j = i & 15;
        float4 v = *(const float4*)(ptsT + ((size_t)b * N_PTS + gi[pos0 + pos]) * 64 + j * 4);
        *(float4*)(A + pos * 68 + j * 4) = v;
    }
    __syncthreads();
    if (t < 128) {
        int g = gi[pos0 + t]; int ci = t >> 5;
        A[t * 68 + 64] = __fsub_rn(xs[g], cent[ci][0]);
        A[t * 68 + 65] = __fsub_rn(ys[g], cent[ci][1]);
        A[t * 68 + 66] = __fsub_rn(zs[g], cent[ci][2]);
        A[t * 68 + 67] = 0.f;
    }
    __syncthreads();

    const int og = t & 15;
    const int pg = t >> 4;
    float acc[8][4];
#pragma unroll
    for (int r = 0; r < 8; ++r)
#pragma unroll
        for (int c = 0; c < 4; ++c) acc[r][c] = 0.f;

    for (int j = 0; j < 17; ++j) {
        float w[4][4];
#pragma unroll
        for (int cc = 0; cc < 4; ++cc) {
            float4 v = *(const float4*)(Wt + (j * 4 + cc) * 64 + og * 4);
            w[cc][0] = v.x; w[cc][1] = v.y; w[cc][2] = v.z; w[cc][3] = v.w;
        }
#pragma unroll
        for (int r = 0; r < 8; ++r) {
            float4 v = *(const float4*)(A + (pg + r * 16) * 68 + j * 4);
#pragma unroll
            for (int co = 0; co < 4; ++co) {
                float s = acc[r][co];
                s = fmaf(v.x, w[0][co], s);
                s = fmaf(v.y, w[1][co], s);
                s = fmaf(v.z, w[2][co], s);
                s = fmaf(v.w, w[3][co], s);
                acc[r][co] = s;
            }
        }
    }

    float sum[4] = {0,0,0,0}, ssq[4] = {0,0,0,0};
#pragma unroll
    for (int r = 0; r < 8; ++r)
#pragma unroll
        for (int c = 0; c < 4; ++c) {
            float yv = acc[r][c] + bsh[og * 4 + c];
            sum[c] += yv; ssq[c] = fmaf(yv, yv, ssq[c]);
        }
#pragma unroll
    for (int c = 0; c < 4; ++c) {
        atomicAdd(&sred[og * 4 + c], sum[c]);
        atomicAdd(&sred[64 + og * 4 + c], ssq[c]);
    }
    __syncthreads();
    if (t < 128) atomicAdd(&stats0[t], sred[t]);
}

// ======================= K2: recompute mm0 -> BN0 -> mm1, layer-1 stats =======================
__global__ __launch_bounds__(256) void conv1_stats_kernel(
    const float* __restrict__ xyz, const float* __restrict__ ptsT,
    const int* __restrict__ fps_idx, const int* __restrict__ gi,
    const float* __restrict__ W0, const float* __restrict__ bias0,
    const float* __restrict__ W1, const float* __restrict__ bias1,
    const float* __restrict__ scl0, const float* __restrict__ sh0,
    float* __restrict__ stats1)
{
    __shared__ float A[64 * 68];
    __shared__ float W0t[68 * 64];
    __shared__ float W1t[64 * 64];
    __shared__ float cent[2][3];
    __shared__ float b0sh[64], b1sh[64], s0sh[64], h0sh[64];
    __shared__ float sred[128];

    const int t = threadIdx.x;
    const size_t pos0 = (size_t)blockIdx.x * 64;
    const int b  = (int)(pos0 >> 15);
    const int s0 = (int)((pos0 >> 5) & (S_PTS - 1));
    const float* xs = xyz + (size_t)b * 3 * N_PTS;
    const float* ys = xs + N_PTS;
    const float* zs = ys + N_PTS;

    if (t < 2) {
        int fi = fps_idx[b * S_PTS + s0 + t];
        cent[t][0] = xs[fi]; cent[t][1] = ys[fi]; cent[t][2] = zs[fi];
    }
    if (t >= 64 && t < 128) { b0sh[t-64] = bias0[t-64]; b1sh[t-64] = bias1[t-64]; }
    if (t >= 128 && t < 192) { s0sh[t-128] = scl0[t-128]; h0sh[t-128] = sh0[t-128]; }
    if (t >= 192) { sred[t-192] = 0.f; sred[t-128] = 0.f; }
    for (int i = t; i < 68 * 64; i += 256) {
        int c = i >> 6, o = i & 63;
        float v = 0.f;
        if (c < 64) v = W0[o * 67 + 3 + c];
        else if (c < 67) v = W0[o * 67 + (c - 64)];
        W0t[i] = v;
    }
    for (int i = t; i < 64 * 64; i += 256) { int c = i >> 6, o = i & 63; W1t[i] = W1[o * 64 + c]; }
    for (int i = t; i < 64 * 16; i += 256) {
        int pos = i >> 4, j = i & 15;
        float4 v = *(const float4*)(ptsT + ((size_t)b * N_PTS + gi[pos0 + pos]) * 64 + j * 4);
        *(float4*)(A + pos * 68 + j * 4) = v;
    }
    __syncthreads();
    if (t < 64) {
        int g = gi[pos0 + t]; int ci = t >> 5;
        A[t * 68 + 64] = __fsub_rn(xs[g], cent[ci][0]);
        A[t * 68 + 65] = __fsub_rn(ys[g], cent[ci][1]);
        A[t * 68 + 66] = __fsub_rn(zs[g], cent[ci][2]);
        A[t * 68 + 67] = 0.f;
    }
    __syncthreads();

    const int og = t & 15;
    const int pg = t >> 4;
    float acc[4][4];
#pragma unroll
    for (int r = 0; r < 4; ++r)
#pragma unroll
        for (int c = 0; c < 4; ++c) acc[r][c] = 0.f;

    for (int j = 0; j < 17; ++j) {
        float w[4][4];
#pragma unroll
        for (int cc = 0; cc < 4; ++cc) {
            float4 v = *(const float4*)(W0t + (j * 4 + cc) * 64 + og * 4);
            w[cc][0] = v.x; w[cc][1] = v.y; w[cc][2] = v.z; w[cc][3] = v.w;
        }
#pragma unroll
        for (int r = 0; r < 4; ++r) {
            float4 v = *(const float4*)(A + (pg + r * 16) * 68 + j * 4);
#pragma unroll
            for (int co = 0; co < 4; ++co) {
                float s = acc[r][co];
                s = fmaf(v.x, w[0][co], s);
                s = fmaf(v.y, w[1][co], s);
                s = fmaf(v.z, w[2][co], s);
                s = fmaf(v.w, w[3][co], s);
                acc[r][co] = s;
            }
        }
    }
    __syncthreads();
#pragma unroll
    for (int r = 0; r < 4; ++r) {
        float4 z;
        z.x = fmaxf(fmaf(acc[r][0] + b0sh[og*4+0], s0sh[og*4+0], h0sh[og*4+0]), 0.f);
        z.y = fmaxf(fmaf(acc[r][1] + b0sh[og*4+1], s0sh[og*4+1], h0sh[og*4+1]), 0.f);
        z.z = fmaxf(fmaf(acc[r][2] + b0sh[og*4+2], s0sh[og*4+2], h0sh[og*4+2]), 0.f);
        z.w = fmaxf(fmaf(acc[r][3] + b0sh[og*4+3], s0sh[og*4+3], h0sh[og*4+3]), 0.f);
        *(float4*)(A + (pg + r * 16) * 68 + og * 4) = z;
    }
    __syncthreads();
    float acc1[4][4];
#pragma unroll
    for (int r = 0; r < 4; ++r)
#pragma unroll
        for (int c = 0; c < 4; ++c) acc1[r][c] = 0.f;
    for (int j = 0; j < 16; ++j) {
        float w[4][4];
#pragma unroll
        for (int cc = 0; cc < 4; ++cc) {
            float4 v = *(const float4*)(W1t + (j * 4 + cc) * 64 + og * 4);
            w[cc][0] = v.x; w[cc][1] = v.y; w[cc][2] = v.z; w[cc][3] = v.w;
        }
#pragma unroll
        for (int r = 0; r < 4; ++r) {
            float4 v = *(const float4*)(A + (pg + r * 16) * 68 + j * 4);
#pragma unroll
            for (int co = 0; co < 4; ++co) {
                float s = acc1[r][co];
                s = fmaf(v.x, w[0][co], s);
                s = fmaf(v.y, w[1][co], s);
                s = fmaf(v.z, w[2][co], s);
                s = fmaf(v.w, w[3][co], s);
                acc1[r][co] = s;
            }
        }
    }
    float sum[4] = {0,0,0,0}, ssq[4] = {0,0,0,0};
#pragma unroll
    for (int r = 0; r < 4; ++r)
#pragma unroll
        for (int c = 0; c < 4; ++c) {
            float yv = acc1[r][c] + b1sh[og * 4 + c];
            sum[c] += yv; ssq[c] = fmaf(yv, yv, ssq[c]);
        }
#pragma unroll
    for (int c = 0; c < 4; ++c) {
        atomicAdd(&sred[og * 4 + c], sum[c]);
        atomicAdd(&sred[64 + og * 4 + c], ssq[c]);
    }
    __syncthreads();
    if (t < 128) atomicAdd(&stats1[t], sred[t]);
}

// ======================= K3: full chain -> layer-2 stats + K-max =======================
__global__ __launch_bounds__(256) void conv2_final_kernel(
    const float* __restrict__ xyz, const float* __restrict__ ptsT,
    const int* __restrict__ fps_idx, const int* __restrict__ gi,
    const float* __restrict__ W0, const float* __restrict__ bias0,
    const float* __restrict__ W1, const float* __restrict__ bias1,
    const float* __restrict__ W2, const float* __restrict__ bias2,
    const float* __restrict__ scl0, const float* __restrict__ sh0,
    const float* __restrict__ scl1, const float* __restrict__ sh1,
    float* __restrict__ mout, float* __restrict__ stats2)
{
    __shared__ float A[64 * 68];
    __shared__ float Wb[8192];
    __shared__ float cent[2][3];
    __shared__ float b0sh[64], b1sh[64], b2sh[128];
    __shared__ float s0sh[64], h0sh[64], s1sh[64], h1sh[64];
    __shared__ float sred[256];
    __shared__ float maxbuf[2][8][128];

    const int t = threadIdx.x;
    const size_t pos0 = (size_t)blockIdx.x * 64;
    const int b  = (int)(pos0 >> 15);
    const int s0 = (int)((pos0 >> 5) & (S_PTS - 1));
    const float* xs = xyz + (size_t)b * 3 * N_PTS;
    const float* ys = xs + N_PTS;
    const float* zs = ys + N_PTS;

    if (t < 2) {
        int fi = fps_idx[b * S_PTS + s0 + t];
        cent[t][0] = xs[fi]; cent[t][1] = ys[fi]; cent[t][2] = zs[fi];
    }
    if (t < 64) { s0sh[t] = scl0[t]; h0sh[t] = sh0[t]; }
    else if (t < 128) { s1sh[t-64] = scl1[t-64]; h1sh[t-64] = sh1[t-64]; }
    else if (t < 192) { b0sh[t-128] = bias0[t-128]; b1sh[t-128] = bias1[t-128]; }
    else { int q = (t - 192) * 4; sred[q]=0.f; sred[q+1]=0.f; sred[q+2]=0.f; sred[q+3]=0.f; }
    if (t < 128) b2sh[t] = bias2[t];
    for (int i = t; i < 68 * 64; i += 256) {
        int c = i >> 6, o = i & 63;
        float v = 0.f;
        if (c < 64) v = W0[o * 67 + 3 + c];
        else if (c < 67) v = W0[o * 67 + (c - 64)];
        Wb[i] = v;
    }
    for (int i = t; i < 64 * 16; i += 256) {
        int pos = i >> 4, j = i & 15;
        float4 v = *(const float4*)(ptsT + ((size_t)b * N_PTS + gi[pos0 + pos]) * 64 + j * 4);
        *(float4*)(A + pos * 68 + j * 4) = v;
    }
    __syncthreads();
    if (t < 64) {
        int g = gi[pos0 + t]; int ci = t >> 5;
        A[t * 68 + 64] = __fsub_rn(xs[g], cent[ci][0]);
        A[t * 68 + 65] = __fsub_rn(ys[g], cent[ci][1]);
        A[t * 68 + 66] = __fsub_rn(zs[g], cent[ci][2]);
        A[t * 68 + 67] = 0.f;
    }
    __syncthreads();

    const int og = t & 15;
    const int pg = t >> 4;
    float acc[4][4];
#pragma unroll
    for (int r = 0; r < 4; ++r)
#pragma unroll
        for (int c = 0; c < 4; ++c) acc[r][c] = 0.f;
    for (int j = 0; j < 17; ++j) {
        float w[4][4];
#pragma unroll
        for (int cc = 0; cc < 4; ++cc) {
            float4 v = *(const float4*)(Wb + (j * 4 + cc) * 64 + og * 4);
            w[cc][0] = v.x; w[cc][1] = v.y; w[cc][2] = v.z; w[cc][3] = v.w;
        }
#pragma unroll
        for (int r = 0; r < 4; ++r) {
            float4 v = *(const float4*)(A + (pg + r * 16) * 68 + j * 4);
#pragma unroll
            for (int co = 0; co < 4; ++co) {
                float s = acc[r][co];
                s = fmaf(v.x, w[0][co], s);
                s = fmaf(v.y, w[1][co], s);
                s = fmaf(v.z, w[2][co], s);
                s = fmaf(v.w, w[3][co], s);
                acc[r][co] = s;
            }
        }
    }
    __syncthreads();
#pragma unroll
    for (int r = 0; r < 4; ++r) {
        float4 z;
        z.x = fmaxf(fmaf(acc[r][0] + b0sh[og*4+0], s0sh[og*4+0], h0sh[og*4+0]), 0.f);
        z.y = fmaxf(fmaf(acc[r][1] + b0sh[og*4+1], s0sh[og*4+1], h0sh[og*4+1]), 0.f);
        z.z = fmaxf(fmaf(acc[r][2] + b0sh[og*4+2], s0sh[og*4+2], h0sh[og*4+2]), 0.f);
        z.w = fmaxf(fmaf(acc[r][3] + b0sh[og*4+3], s0sh[og*4+3], h0sh[og*4+3]), 0.f);
        *(float4*)(A + (pg + r * 16) * 68 + og * 4) = z;
    }
    for (int i = t; i < 64 * 64; i += 256) { int c = i >> 6, o = i & 63; Wb[i] = W1[o * 64 + c]; }
    __syncthreads();
    float acc1[4][4];
#pragma unroll
    for (int r = 0; r < 4; ++r)
#pragma unroll
        for (int c = 0; c < 4; ++c) acc1[r][c] = 0.f;
    for (int j = 0; j < 16; ++j) {
        float w[4][4];
#pragma unroll
        for (int cc = 0; cc < 4; ++cc) {
            float4 v = *(const float4*)(Wb + (j * 4 + cc) * 64 + og * 4);
            w[cc][0] = v.x; w[cc][1] = v.y; w[cc][2] = v.z; w[cc][3] = v.w;
        }
#pragma unroll
        for (int r = 0; r < 4; ++r) {
            float4 v = *(const float4*)(A + (pg + r * 16) * 68 + j * 4);
#pragma unroll
            for (int co = 0; co < 4; ++co) {
                float s = acc1[r][co];
                s = fmaf(v.x, w[0][co], s);
                s = fmaf(v.y, w[1][co], s);
                s = fmaf(v.z, w[2][co], s);
                s = fmaf(v.w, w[3][co], s);
                acc1[r][co] = s;
            }
        }
    }
    __syncthreads();
#pragma unroll
    for (int r = 0; r < 4; ++r) {
        float4 z;
        z.x = fmaxf(fmaf(acc1[r][0] + b1sh[og*4+0], s1sh[og*4+0], h1sh[og*4+0]), 0.f);
        z.y = fmaxf(fmaf(acc1[r][1] + b1sh[og*4+1], s1sh[og*4+1], h1sh[og*4+1]), 0.f);
        z.z = fmaxf(fmaf(acc1[r][2] + b1sh[og*4+2], s1sh[og*4+2], h1sh[og*4+2]), 0.f);
        z.w = fmaxf(fmaf(acc1[r][3] + b1sh[og*4+3], s1sh[og*4+3], h1sh[og*4+3]), 0.f);
        *(float4*)(A + (pg + r * 16) * 68 + og * 4) = z;
    }
    for (int i = t; i < 64 * 128; i += 256) { int c = i >> 7, o = i & 127; Wb[i] = W2[o * 64 + c]; }
    __syncthreads();
    const int og2 = t & 31;
    const int pg2 = t >> 5;
    float acc2[8][4];
#pragma unroll
    for (int r = 0; r < 8; ++r)
#pragma unroll
        for (int c = 0; c < 4; ++c) acc2[r][c] = 0.f;
    for (int j = 0; j < 16; ++j) {
        float w[4][4];
#pragma unroll
        for (int cc = 0; cc < 4; ++cc) {
            float4 v = *(const float4*)(Wb + (j * 4 + cc) * 128 + og2 * 4);
            w[cc][0] = v.x; w[cc][1] = v.y; w[cc][2] = v.z; w[cc][3] = v.w;
        }
#pragma unroll
        for (int r = 0; r < 8; ++r) {
            float4 v = *(const float4*)(A + (pg2 + r * 8) * 68 + j * 4);
#pragma unroll
            for (int co = 0; co < 4; ++co) {
                float s = acc2[r][co];
                s = fmaf(v.x, w[0][co], s);
                s = fmaf(v.y, w[1][co], s);
                s = fmaf(v.z, w[2][co], s);
                s = fmaf(v.w, w[3][co], s);
                acc2[r][co] = s;
            }
        }
    }
    float sum[4] = {0,0,0,0}, ssq[4] = {0,0,0,0};
    float mx0[4], mx1[4];
#pragma unroll
    for (int c = 0; c < 4; ++c) { mx0[c] = -3.402823466e38f; mx1[c] = -3.402823466e38f; }
#pragma unroll
    for (int r = 0; r < 8; ++r)
#pragma unroll
        for (int c = 0; c < 4; ++c) {
            float yv = acc2[r][c] + b2sh[og2 * 4 + c];
            sum[c] += yv; ssq[c] = fmaf(yv, yv, ssq[c]);
            if (r < 4) mx0[c] = fmaxf(mx0[c], yv);
            else       mx1[c] = fmaxf(mx1[c], yv);
        }
#pragma unroll
    for (int c = 0; c < 4; ++c) {
        atomicAdd(&sred[og2 * 4 + c], sum[c]);
        atomicAdd(&sred[128 + og2 * 4 + c], ssq[c]);
        maxbuf[0][pg2][og2 * 4 + c] = mx0[c];
        maxbuf[1][pg2][og2 * 4 + c] = mx1[c];
    }
    __syncthreads();
    {
        int cent2 = t >> 7, o = t & 127;
        float v = maxbuf[cent2][0][o];
#pragma unroll
        for (int q = 1; q < 8; ++q) v = fmaxf(v, maxbuf[cent2][q][o]);
        mout[(size_t)(blockIdx.x * 2 + cent2) * 128 + o] = v;
        atomicAdd(&stats2[t], sred[t]);
    }
}

// ======================= BN finalize =======================
__global__ void finalize_kernel(const float* __restrict__ stats, const float* __restrict__ g,
                                const float* __restrict__ beta, float* __restrict__ scl,
                                float* __restrict__ sh, int C)
{
    int c = threadIdx.x;
    if (c >= C) return;
    const float inv = 1.0f / 131072.0f;
    float mean = stats[c] * inv;
    float var  = stats[C + c] * inv - mean * mean;
    var = fmaxf(var, 0.f);
    float s = g[c] / sqrtf(var + 1e-5f);
    scl[c] = s;
    sh[c] = beta[c] - mean * s;
}

// ======================= writeout =======================
__global__ __launch_bounds__(256) void writeout_kernel(
    const float* __restrict__ m, const float* __restrict__ scl,
    const float* __restrict__ sh, float* __restrict__ out)
{
    int idx = blockIdx.x * 256 + threadIdx.x;
    int s = idx & 1023;
    int o = (idx >> 10) & 127;
    int b = idx >> 17;
    float v = m[(size_t)((b << 10) + s) * 128 + o];
    v = fmaxf(fmaf(v, scl[o], sh[o]), 0.f);
    out[idx] = v;
}

// ======================= launch =======================
extern "C" void kernel_launch(void* const* d_in, const int* in_sizes, int n_in,
                              void* d_out, int out_size, void* d_ws, size_t ws_size,
                              hipStream_t stream)
{
    const float* xyz = (const float*)d_in[0];
    const float* pts = (const float*)d_in[1];
    const float* W0  = (const float*)d_in[2];
    const float* b0  = (const float*)d_in[3];
    const float* g0  = (const float*)d_in[4];
    const float* be0 = (const float*)d_in[5];
    const float* W1  = (const float*)d_in[6];
    const float* b1  = (const float*)d_in[7];
    const float* g1  = (const float*)d_in[8];
    const float* be1 = (const float*)d_in[9];
    const float* W2  = (const float*)d_in[10];
    const float* b2  = (const float*)d_in[11];
    const float* g2  = (const float*)d_in[12];
    const float* be2 = (const float*)d_in[13];
    float* out = (float*)d_out;

    char* ws = (char*)d_ws;
    int*   fps_idx = (int*)(ws + 0);              // 16 KB
    int*   gi      = (int*)(ws + 16384);          // 512 KB -> ends 540672
    float* stats   = (float*)(ws + 540672);       // 512 f
    float* ss      = (float*)(ws + 542720);       // 512 f
    float* m       = (float*)(ws + 544768);       // 2 MB
    float* ptsT    = (float*)(ws + 2641920);      // 8 MB -> ends ~10.5 MB
    float *scl0 = ss, *sh0 = ss + 64, *scl1 = ss + 128, *sh1 = ss + 192,
          *scl2 = ss + 256, *sh2 = ss + 384;

    hipMemsetAsync(stats, 0, 2048, stream);

    hipFuncSetAttribute((const void*)fps_kernel,
                        hipFuncAttributeMaxDynamicSharedMemorySize, N_PTS * 16);
    hipLaunchKernelGGL(fps_kernel, dim3(4), dim3(512), N_PTS * 16, stream,
                       xyz, fps_idx, out);
    hipLaunchKernelGGL(transpose_pts_kernel, dim3(128, 4), dim3(256), 0, stream, pts, ptsT);
    hipLaunchKernelGGL(ballq_kernel, dim3(1024), dim3(256), 0, stream, xyz, fps_idx, gi);
    hipLaunchKernelGGL(conv0_stats_kernel, dim3(1024), dim3(256), 0, stream,
                       xyz, ptsT, fps_idx, gi, W0, b0, stats);
    hipLaunchKernelGGL(finalize_kernel, dim3(1), dim3(64), 0, stream, stats, g0, be0, scl0, sh0, 64);
    hipLaunchKernelGGL(conv1_stats_kernel, dim3(2048), dim3(256), 0, stream,
                       xyz, ptsT, fps_idx, gi, W0, b0, W1, b1, scl0, sh0, stats + 128);
    hipLaunchKernelGGL(finalize_kernel, dim3(1), dim3(64), 0, stream, stats + 128, g1, be1, scl1, sh1, 64);
    hipLaunchKernelGGL(conv2_final_kernel, dim3(2048), dim3(256), 0, stream,
                       xyz, ptsT, fps_idx, gi, W0, b0, W1, b1, W2, b2,
                       scl0, sh0, scl1, sh1, m, stats + 256);
    hipLaunchKernelGGL(finalize_kernel, dim3(1), dim3(128), 0, stream, stats + 256, g2, be2, scl2, sh2, 128);
    hipLaunchKernelGGL(writeout_kernel, dim3(2048), dim3(256), 0, stream, m, scl2, sh2, out + 12288);
}